// Round 13
// baseline (386.165 us; speedup 1.0000x reference)
//
#include <hip/hip_runtime.h>
#include <hip/hip_bf16.h>

typedef _Float16 f16_t;
typedef unsigned int uint;
typedef __attribute__((ext_vector_type(8))) _Float16 f16x8;
typedef __attribute__((ext_vector_type(4))) _Float16 f16x4;
typedef __attribute__((ext_vector_type(4))) float f32x4;
typedef __attribute__((ext_vector_type(16))) float f32x16;

// ---------------- repack fp32 [R][4096] -> packed fp16 [R/128][128 kb][128 r][32 c] ----------------
// Bank swizzle baked in: elem pos = r*32 + ((slot ^ ((r>>1)&3))<<3) + (c&7), slot = c>>3.
__global__ __launch_bounds__(256) void repack_x16(const float* __restrict__ src,
                                                  uint16_t* __restrict__ dh)
{
    const int p  = blockIdx.y;
    const int kb = blockIdx.x;
    const int tid = threadIdx.x;
    const int rr = tid >> 3;
    const int k4 = tid & 7;
    const int slot = k4 >> 1;
    const int so   = (k4 & 1) * 4;
    uint16_t* bh = dh + ((size_t)p * 128 + kb) * 4096;
    #pragma unroll
    for (int it = 0; it < 4; ++it) {
        const int r = it * 32 + rr;
        const float4 v = *reinterpret_cast<const float4*>(
            &src[((size_t)p * 128 + r) * 4096 + kb * 32 + k4 * 4]);
        float f[4] = {v.x, v.y, v.z, v.w};
        f16x4 h;
        #pragma unroll
        for (int e = 0; e < 4; ++e) h[e] = (f16_t)f[e];
        const int pos = r * 32 + ((slot ^ ((r >> 1) & 3)) << 3) + so;
        *reinterpret_cast<f16x4*>(&bh[pos]) = h;
    }
}

// combined wq|wk|wv -> 96-row-panel packed fp16: [64 pan][128 kb][96 r][32 c]
__global__ __launch_bounds__(256) void repack_w96_16(const float* __restrict__ wq,
                                                     const float* __restrict__ wk,
                                                     const float* __restrict__ wv,
                                                     uint16_t* __restrict__ dst)
{
    const int kb  = blockIdx.x;
    const int pan = blockIdx.y;
    const int tid = threadIdx.x;
    const int k4 = tid & 7;
    const int slot = k4 >> 1;
    const int so   = (k4 & 1) * 4;
    uint16_t* bh = dst + ((size_t)pan * 128 + kb) * 3072;
    #pragma unroll
    for (int it = 0; it < 3; ++it) {
        const int r = it * 32 + (tid >> 3);
        const int n = pan * 96 + r;
        const float* srow = (n < 4096) ? (wq + (size_t)n * 4096)
                          : (n < 5120) ? (wk + (size_t)(n - 4096) * 4096)
                                       : (wv + (size_t)(n - 5120) * 4096);
        const float4 v = *reinterpret_cast<const float4*>(srow + kb * 32 + k4 * 4);
        float f[4] = {v.x, v.y, v.z, v.w};
        f16x4 h;
        #pragma unroll
        for (int e = 0; e < 4; ++e) h[e] = (f16_t)f[e];
        const int pos = r * 32 + ((slot ^ ((r >> 1) & 3)) << 3) + so;
        *reinterpret_cast<f16x4*>(&bh[pos]) = h;
    }
}

// 128-row-panel fp16 repack (wo)
__global__ __launch_bounds__(256) void repack_h16(const float* __restrict__ src,
                                                  uint16_t* __restrict__ dh)
{
    const int p  = blockIdx.y;
    const int kb = blockIdx.x;
    const int tid = threadIdx.x;
    const int rr = tid >> 3;
    const int k4 = tid & 7;
    const int slot = k4 >> 1;
    const int so   = (k4 & 1) * 4;
    uint16_t* bh = dh + ((size_t)p * 128 + kb) * 4096;
    #pragma unroll
    for (int it = 0; it < 4; ++it) {
        const int r = it * 32 + rr;
        const float4 v = *reinterpret_cast<const float4*>(
            &src[((size_t)p * 128 + r) * 4096 + kb * 32 + k4 * 4]);
        float f[4] = {v.x, v.y, v.z, v.w};
        f16x4 h;
        #pragma unroll
        for (int e = 0; e < 4; ++e) h[e] = (f16_t)f[e];
        const int pos = r * 32 + ((slot ^ ((r >> 1) & 3)) << 3) + so;
        *reinterpret_cast<f16x4*>(&bh[pos]) = h;
    }
}

// ---------------- QKV GEMM: 128x192, fp16, BK=64, 2-buf, grid 512 (2 blocks/CU) ----------------
__global__ __launch_bounds__(512) void gemm_qkv9(const uint16_t* __restrict__ xh,
                                                 const uint16_t* __restrict__ wqkv,
                                                 float* __restrict__ xq,
                                                 float* __restrict__ xk,
                                                 float* __restrict__ xv)
{
    __shared__ char lds[2][40960];   // per buf: A 16K ([kk2][128r][32c]) | B 24K ([pan2][kk2][96r][32c])

    const int bid = blockIdx.x;
    const int swz = (bid & 7) * 64 + (bid >> 3);   // 512 blocks, XCD-chunked
    const int by = swz >> 5;                        // 0..15
    const int bx = swz & 31;                        // 0..31
    const int tid = threadIdx.x;
    const int w = tid >> 6, lane = tid & 63;
    const int wm = w >> 2, wn = w & 3;              // 2 x 4 waves -> wave tile 64x48
    const int fr = lane & 15, s4 = lane >> 4;

    // 40 chunks of 1 KB: 0..15 A, 16..39 B; wave w stages c = w + 8i, i=0..4
    const uint16_t* sp[5];
    int dof[5];
    int stridec[5];
    #pragma unroll
    for (int i = 0; i < 5; ++i) {
        const int c = w + 8 * i;
        if (c < 16) {
            const int kk = c >> 3, inner = c & 7;
            sp[i] = xh + (size_t)by * 524288 + kk * 4096 + inner * 512 + lane * 8;
            dof[i] = c * 1024;
            stridec[i] = 8192;
        } else {
            const int cb = c - 16;                 // 0..23
            const int pan = cb / 12, rem = cb % 12;
            const int kk = rem / 6, inner = rem % 6;
            sp[i] = wqkv + (size_t)(bx * 2 + pan) * 393216 + kk * 3072 + inner * 512 + lane * 8;
            dof[i] = 16384 + cb * 1024;
            stridec[i] = 6144;
        }
    }

    f32x4 acc[4][3] = {};

    // prologue: stage tile 0
    #pragma unroll
    for (int i = 0; i < 5; ++i)
        __builtin_amdgcn_global_load_lds(
            (const __attribute__((address_space(1))) void*)(sp[i]),
            (__attribute__((address_space(3))) void*)(&lds[0][0] + dof[i]), 16, 0, 0);
    asm volatile("s_waitcnt vmcnt(0)" ::: "memory");
    __builtin_amdgcn_s_barrier();
    __builtin_amdgcn_sched_barrier(0);

    for (int t = 0; t < 64; ++t) {
        const char* b = &lds[t & 1][0];
        if (t + 1 < 64) {
            char* nb = &lds[(t + 1) & 1][0];
            #pragma unroll
            for (int i = 0; i < 5; ++i)
                __builtin_amdgcn_global_load_lds(
                    (const __attribute__((address_space(1))) void*)(sp[i] + (size_t)(t + 1) * stridec[i]),
                    (__attribute__((address_space(3))) void*)(nb + dof[i]), 16, 0, 0);
        }
        #pragma unroll
        for (int kk = 0; kk < 2; ++kk) {
            f16x8 fb[3];
            #pragma unroll
            for (int j = 0; j < 3; ++j) {
                const int cbp = wn * 48 + j * 16 + fr;           // 0..191
                const int pan = (cbp >= 96) ? 1 : 0;
                const int rb = cbp - pan * 96;
                fb[j] = *reinterpret_cast<const f16x8*>(
                    b + 16384 + pan * 12288 + kk * 6144 + rb * 64 + ((s4 ^ ((rb >> 1) & 3)) << 4));
            }
            #pragma unroll
            for (int ri = 0; ri < 4; ++ri) {
                const int rloc = wm * 64 + ri * 16 + fr;         // 0..127
                f16x8 fh = *reinterpret_cast<const f16x8*>(
                    b + kk * 8192 + rloc * 64 + ((s4 ^ ((rloc >> 1) & 3)) << 4));
                __builtin_amdgcn_s_setprio(1);
                #pragma unroll
                for (int j = 0; j < 3; ++j)
                    acc[ri][j] = __builtin_amdgcn_mfma_f32_16x16x32_f16(fh, fb[j], acc[ri][j], 0, 0, 0);
                __builtin_amdgcn_s_setprio(0);
            }
        }
        asm volatile("s_waitcnt vmcnt(0)" ::: "memory");
        __builtin_amdgcn_s_barrier();
        __builtin_amdgcn_sched_barrier(0);
    }

    const int r0 = by * 128 + wm * 64 + s4 * 4;
    const int c0 = bx * 192 + wn * 48 + fr;
    #pragma unroll
    for (int ri = 0; ri < 4; ++ri)
        #pragma unroll
        for (int j = 0; j < 3; ++j) {
            const int col = c0 + j * 16;
            #pragma unroll
            for (int rr = 0; rr < 4; ++rr) {
                const int row = r0 + ri * 16 + rr;
                if (col < 4096)      xq[(size_t)row * 4096 + col] = acc[ri][j][rr];
                else if (col < 5120) xk[(size_t)row * 1024 + (col - 4096)] = acc[ri][j][rr];
                else                 xv[(size_t)row * 1024 + (col - 5120)] = acc[ri][j][rr];
            }
        }
}

// ---------------- Output GEMM: 128x128, fp16, BK=64, 2-buf, grid 512 (2 blocks/CU) ----------------
__global__ __launch_bounds__(512) void gemm_out9(const uint16_t* __restrict__ aoh,
                                                 const uint16_t* __restrict__ woh,
                                                 float* __restrict__ out)
{
    __shared__ char lds[2][32768];   // per buf: A 16K | B 16K ([kk2][128r][32c])

    const int bid = blockIdx.x;
    const int swz = (bid & 7) * 64 + (bid >> 3);
    const int by = swz >> 5;    // 0..15
    const int bx = swz & 31;    // 0..31
    const int tid = threadIdx.x;
    const int w = tid >> 6, lane = tid & 63;
    const int wm = w >> 2, wn = w & 3;              // wave tile 64x32
    const int fr = lane & 15, s4 = lane >> 4;

    // 32 chunks: 0..15 A, 16..31 B; wave w stages c = w + 8i, i=0..3
    const uint16_t* sp[4];
    int dof[4];
    #pragma unroll
    for (int i = 0; i < 4; ++i) {
        const int c = w + 8 * i;
        if (c < 16) {
            const int kk = c >> 3, inner = c & 7;
            sp[i] = aoh + (size_t)by * 524288 + kk * 4096 + inner * 512 + lane * 8;
            dof[i] = c * 1024;
        } else {
            const int cb = c - 16;
            const int kk = cb >> 3, inner = cb & 7;
            sp[i] = woh + (size_t)bx * 524288 + kk * 4096 + inner * 512 + lane * 8;
            dof[i] = 16384 + cb * 1024;
        }
    }

    f32x4 acc[4][2] = {};

    #pragma unroll
    for (int i = 0; i < 4; ++i)
        __builtin_amdgcn_global_load_lds(
            (const __attribute__((address_space(1))) void*)(sp[i]),
            (__attribute__((address_space(3))) void*)(&lds[0][0] + dof[i]), 16, 0, 0);
    asm volatile("s_waitcnt vmcnt(0)" ::: "memory");
    __builtin_amdgcn_s_barrier();
    __builtin_amdgcn_sched_barrier(0);

    for (int t = 0; t < 64; ++t) {
        const char* b = &lds[t & 1][0];
        if (t + 1 < 64) {
            char* nb = &lds[(t + 1) & 1][0];
            #pragma unroll
            for (int i = 0; i < 4; ++i)
                __builtin_amdgcn_global_load_lds(
                    (const __attribute__((address_space(1))) void*)(sp[i] + (size_t)(t + 1) * 8192),
                    (__attribute__((address_space(3))) void*)(nb + dof[i]), 16, 0, 0);
        }
        #pragma unroll
        for (int kk = 0; kk < 2; ++kk) {
            f16x8 fb[2];
            #pragma unroll
            for (int j = 0; j < 2; ++j) {
                const int cbp = wn * 32 + j * 16 + fr;
                fb[j] = *reinterpret_cast<const f16x8*>(
                    b + 16384 + kk * 8192 + cbp * 64 + ((s4 ^ ((cbp >> 1) & 3)) << 4));
            }
            #pragma unroll
            for (int ri = 0; ri < 4; ++ri) {
                const int rloc = wm * 64 + ri * 16 + fr;
                f16x8 fh = *reinterpret_cast<const f16x8*>(
                    b + kk * 8192 + rloc * 64 + ((s4 ^ ((rloc >> 1) & 3)) << 4));
                __builtin_amdgcn_s_setprio(1);
                #pragma unroll
                for (int j = 0; j < 2; ++j)
                    acc[ri][j] = __builtin_amdgcn_mfma_f32_16x16x32_f16(fh, fb[j], acc[ri][j], 0, 0, 0);
                __builtin_amdgcn_s_setprio(0);
            }
        }
        asm volatile("s_waitcnt vmcnt(0)" ::: "memory");
        __builtin_amdgcn_s_barrier();
        __builtin_amdgcn_sched_barrier(0);
    }

    const int r0 = by * 128 + wm * 64 + s4 * 4;
    const int c0 = bx * 128 + wn * 32 + fr;
    #pragma unroll
    for (int ri = 0; ri < 4; ++ri)
        #pragma unroll
        for (int j = 0; j < 2; ++j)
            #pragma unroll
            for (int rr = 0; rr < 4; ++rr)
                out[(size_t)(r0 + ri * 16 + rr) * 4096 + c0 + j * 16] = acc[ri][j][rr];
}

// ---------------- RoPE in place; Q additionally scaled by 1/sqrt(128) ----------------
__global__ __launch_bounds__(256) void rope_k(float* __restrict__ xq, float* __restrict__ xk)
{
    const int idx = blockIdx.x * 256 + threadIdx.x;
    const int TOTQ = 2048 * 32 * 64;
    int s, j;
    float* base;
    bool isq = idx < TOTQ;
    if (isq) {
        s = idx >> 11;
        const int rem = idx & 2047;
        j = rem & 63;
        base = xq + (size_t)s * 4096 + (rem >> 6) * 128 + 2 * j;
    } else {
        const int i2 = idx - TOTQ;
        s = i2 >> 9;
        const int rem = i2 & 511;
        j = rem & 63;
        base = xk + (size_t)s * 1024 + (rem >> 6) * 128 + 2 * j;
    }
    const float invf = exp2f(-(float)j * (13.287712379549449f / 64.0f));
    const float ang = (float)s * invf;
    float sn, cs;
    sincosf(ang, &sn, &cs);
    float2 v = *reinterpret_cast<float2*>(base);
    float2 r;
    r.x = v.x * cs - v.y * sn;
    r.y = v.x * sn + v.y * cs;
    if (isq) { r.x *= 0.08838834764831845f; r.y *= 0.08838834764831845f; }
    *reinterpret_cast<float2*>(base) = r;
}

// ---------------- Convert roped K and raw V to blocked+swizzled fp16 tiles ----------------
// Tile = 8192 uint16 (16 KB): K [32 kv][128 d] at 0, Vt [128 d][32 kv] at 4096.
__global__ __launch_bounds__(256) void conv_kv(const float* __restrict__ xk,
                                               const float* __restrict__ xv,
                                               uint16_t* __restrict__ kvg)
{
    __shared__ float V[32][129];
    const int t = blockIdx.x;
    const int h = blockIdx.y;
    const int tid = threadIdx.x;
    uint16_t* tile = kvg + ((size_t)(h * 64 + t)) * 8192;

    #pragma unroll
    for (int i = 0; i < 4; ++i) {
        int v = i * 256 + tid;
        int row = v >> 5, c4 = (v & 31) * 4;
        *reinterpret_cast<float4*>(&V[row][c4]) =
            *reinterpret_cast<const float4*>(&xv[(size_t)(t * 32 + row) * 1024 + h * 128 + c4]);
    }

    {
        const int r = tid >> 3;
        const int d0 = (tid & 7) * 16;
        float f[16];
        const float* kr = &xk[(size_t)(t * 32 + r) * 1024 + h * 128 + d0];
        *reinterpret_cast<float4*>(&f[0])  = *reinterpret_cast<const float4*>(kr);
        *reinterpret_cast<float4*>(&f[4])  = *reinterpret_cast<const float4*>(kr + 4);
        *reinterpret_cast<float4*>(&f[8])  = *reinterpret_cast<const float4*>(kr + 8);
        *reinterpret_cast<float4*>(&f[12]) = *reinterpret_cast<const float4*>(kr + 12);
        #pragma unroll
        for (int cc = 0; cc < 2; ++cc) {
            f16x8 hv;
            #pragma unroll
            for (int e = 0; e < 8; ++e) hv[e] = (f16_t)f[cc * 8 + e];
            const int c = (d0 >> 3) + cc;
            const int pos = r * 128 + ((c ^ (r & 15)) << 3);
            *reinterpret_cast<f16x8*>(&tile[pos]) = hv;
        }
    }
    __syncthreads();
    {
        const int d = tid >> 1;
        const int k0 = (tid & 1) * 16;
        float g[16];
        #pragma unroll
        for (int j = 0; j < 16; ++j) g[j] = V[k0 + j][d];
        #pragma unroll
        for (int cc = 0; cc < 2; ++cc) {
            f16x8 hv;
            #pragma unroll
            for (int e = 0; e < 8; ++e) hv[e] = (f16_t)g[cc * 8 + e];
            const int c = (k0 >> 3) + cc;
            const int pos = 4096 + d * 32 + ((c ^ (d & 3)) << 3);
            *reinterpret_cast<f16x8*>(&tile[pos]) = hv;
        }
    }
}

// ---------------- MFMA flash attention (full fp16; defer-max; fp16 packed epilogue) ----------------
__device__ __forceinline__ uint cvtpkh(float lo, float hi) {
    uint r;
    asm("v_cvt_pkrtz_f16_f32 %0, %1, %2" : "=v"(r) : "v"(lo), "v"(hi));
    return r;
}
__device__ __forceinline__ void permswap(uint& a, uint& b) {
    asm("v_permlane32_swap_b32 %0, %1" : "+v"(a), "+v"(b));
}
__device__ __forceinline__ f16x8 pack4h(uint w0, uint w1, uint w2, uint w3) {
    union { uint u[4]; f16x8 v; } t;
    t.u[0] = w0; t.u[1] = w1; t.u[2] = w2; t.u[3] = w3;
    return t.v;
}

__global__ __launch_bounds__(512, 2) void attn_mfma(const float* __restrict__ xq,
                                                    const uint16_t* __restrict__ kvg,
                                                    uint16_t* __restrict__ aoh)
{
    __shared__ char lds[2][16384];

    const int b = blockIdx.x;
    const int kvh = b & 7;
    const int r = b >> 3;
    const int h = kvh * 4 + (r & 3);
    const int q0 = (r >> 2) * 256;
    const int tid = threadIdx.x;
    const int w = tid >> 6;
    const int lane = tid & 63;
    const int ln31 = lane & 31;
    const int hi = lane >> 5;

    const int q = q0 + w * 32 + ln31;
    const float* qrow = xq + (size_t)q * 4096 + h * 128;
    f16x8 Qh[8];
    #pragma unroll
    for (int ks = 0; ks < 8; ++ks) {
        float f[8];
        *reinterpret_cast<float4*>(&f[0]) = *reinterpret_cast<const float4*>(qrow + ks * 16 + hi * 8);
        *reinterpret_cast<float4*>(&f[4]) = *reinterpret_cast<const float4*>(qrow + ks * 16 + hi * 8 + 4);
        #pragma unroll
        for (int e = 0; e < 8; ++e) Qh[ks][e] = (f16_t)f[e];
    }

    const char* gkv = (const char*)kvg + (size_t)kvh * 64 * 16384;

    f32x16 oacc[4] = {{}, {}, {}, {}};
    float m = -3.0e38f, l = 0.f;

    {
        #pragma unroll
        for (int i = 0; i < 2; ++i) {
            const int chunk = i * 8 + w;
            __builtin_amdgcn_global_load_lds(
                (const __attribute__((address_space(1))) void*)(gkv + chunk * 1024 + lane * 16),
                (__attribute__((address_space(3))) void*)(&lds[0][chunk * 1024]),
                16, 0, 0);
        }
    }

    for (int t = 0; t < 64; ++t) {
        __syncthreads();
        if (t + 1 < 64) {
            const char* g = gkv + (size_t)(t + 1) * 16384;
            const int buf = (t + 1) & 1;
            #pragma unroll
            for (int i = 0; i < 2; ++i) {
                const int chunk = i * 8 + w;
                __builtin_amdgcn_global_load_lds(
                    (const __attribute__((address_space(1))) void*)(g + chunk * 1024 + lane * 16),
                    (__attribute__((address_space(3))) void*)(&lds[buf][chunk * 1024]),
                    16, 0, 0);
            }
        }
        const int cur = t & 1;
        const char* Kf = lds[cur];
        const char* Vf = lds[cur] + 8192;

        f32x16 s0 = {}, s1 = {};
        __builtin_amdgcn_s_setprio(1);
        #pragma unroll
        for (int ks = 0; ks < 8; ++ks) {
            const int byt = ln31 * 256 + ((ks * 32 + hi * 16) ^ ((ln31 & 15) << 4));
            f16x8 a = *reinterpret_cast<const f16x8*>(Kf + byt);
            if (ks & 1) s1 = __builtin_amdgcn_mfma_f32_32x32x16_f16(a, Qh[ks], s1, 0, 0, 0);
            else        s0 = __builtin_amdgcn_mfma_f32_32x32x16_f16(a, Qh[ks], s0, 0, 0, 0);
        }
        __builtin_amdgcn_s_setprio(0);
        f32x16 s = s0 + s1;

        float pmax = s[0];
        #pragma unroll
        for (int jj = 1; jj < 16; ++jj) pmax = fmaxf(pmax, s[jj]);
        pmax = fmaxf(pmax, __shfl_xor(pmax, 32));
        if (!__all(pmax - m <= 8.0f)) {
            const float mnew = fmaxf(m, pmax);
            const float corr = __expf(m - mnew);
            l *= corr;
            #pragma unroll
            for (int dt = 0; dt < 4; ++dt) oacc[dt] *= corr;
            m = mnew;
        }
        float psum = 0.f;
        #pragma unroll
        for (int jj = 0; jj < 16; ++jj) {
            float pv = __expf(s[jj] - m);
            s[jj] = pv;
            psum += pv;
        }
        psum += __shfl_xor(psum, 32);
        l += psum;

        #pragma unroll
        for (int ks = 0; ks < 2; ++ks) {
            const int b0 = ks * 8;
            uint wa = cvtpkh(s[b0 + 0], s[b0 + 1]);
            uint wb = cvtpkh(s[b0 + 2], s[b0 + 3]);
            uint wc = cvtpkh(s[b0 + 4], s[b0 + 5]);
            uint wd = cvtpkh(s[b0 + 6], s[b0 + 7]);
            permswap(wa, wc); permswap(wb, wd);
            f16x8 Pf = pack4h(wa, wb, wc, wd);
            __builtin_amdgcn_s_setprio(1);
            #pragma unroll
            for (int dt = 0; dt < 4; ++dt) {
                const int row = dt * 32 + ln31;
                const int byt = row * 64 + ((ks * 32 + hi * 16) ^ ((row & 3) << 4));
                f16x8 vh = *reinterpret_cast<const f16x8*>(Vf + byt);
                oacc[dt] = __builtin_amdgcn_mfma_f32_32x32x16_f16(vh, Pf, oacc[dt], 0, 0, 0);
            }
            __builtin_amdgcn_s_setprio(0);
        }
    }

    // ---- epilogue: O -> fp16, packed layout for gemm_out9 ----
    const float invl = 1.0f / l;
    const int p   = q >> 7;
    const int rr_ = q & 127;
    const int rsw = (rr_ >> 1) & 3;
    #pragma unroll
    for (int dt = 0; dt < 4; ++dt) {
        const int kb = h * 4 + dt;
        uint16_t* bh = aoh + ((size_t)p * 128 + kb) * 4096;
        #pragma unroll
        for (int g4 = 0; g4 < 4; ++g4) {
            f16x4 hv;
            #pragma unroll
            for (int e = 0; e < 4; ++e)
                hv[e] = (f16_t)(oacc[dt][g4 * 4 + e] * invl);
            const int pos = rr_ * 32 + ((g4 ^ rsw) << 3) + 4 * hi;
            *reinterpret_cast<f16x4*>(&bh[pos]) = hv;
        }
    }
}

extern "C" void kernel_launch(void* const* d_in, const int* in_sizes, int n_in,
                              void* d_out, int out_size, void* d_ws, size_t ws_size,
                              hipStream_t stream)
{
    const float* x  = (const float*)d_in[0];
    const float* wq = (const float*)d_in[1];
    const float* wk = (const float*)d_in[2];
    const float* wv = (const float*)d_in[3];
    const float* wo = (const float*)d_in[4];
    float* out = (float*)d_out;

    float* ws = (float*)d_ws;
    float*    xq   = ws;                           // [0, 8388608)
    uint16_t* kvg  = (uint16_t*)(ws + 8388608);    // fp16 K/V tiles (8.4 MB)
    float*    xk   = ws + 12582912;
    float*    xv   = ws + 14680064;
    uint16_t* aoh  = (uint16_t*)(ws + 12582912);   // reuses xk slot after conv_kv
    uint16_t* xh   = (uint16_t*)(ws + 20971520);   // fp16 packed x
    uint16_t* wqkv = (uint16_t*)(ws + 29360128);   // fp16 packed wq|wk|wv
    uint16_t* woh  = (uint16_t*)(ws + 41943040);   // fp16 packed wo

    dim3 blk(256);
    repack_x16   <<<dim3(128, 16), blk, 0, stream>>>(x, xh);
    repack_w96_16<<<dim3(128, 64), blk, 0, stream>>>(wq, wk, wv, wqkv);
    gemm_qkv9    <<<dim3(512), dim3(512), 0, stream>>>(xh, wqkv, xq, xk, xv);
    repack_h16   <<<dim3(128, 32), blk, 0, stream>>>(wo, woh);
    rope_k       <<<dim3(20480), blk, 0, stream>>>(xq, xk);
    conv_kv      <<<dim3(64, 8), blk, 0, stream>>>(xk, xv, kvg);
    attn_mfma    <<<dim3(256), dim3(512), 0, stream>>>(xq, kvg, aoh);
    gemm_out9    <<<dim3(512), dim3(512), 0, stream>>>(aoh, woh, out);
}

// Round 14
// 366.268 us; speedup vs baseline: 1.0543x; 1.0543x over previous
//
#include <hip/hip_runtime.h>
#include <hip/hip_bf16.h>

typedef _Float16 f16_t;
typedef unsigned int uint;
typedef __attribute__((ext_vector_type(8))) _Float16 f16x8;
typedef __attribute__((ext_vector_type(4))) _Float16 f16x4;
typedef __attribute__((ext_vector_type(4))) float f32x4;
typedef __attribute__((ext_vector_type(16))) float f32x16;

#define ROPE_C (13.287712379549449f / 64.0f)   // log2(10000)/64; invf(j)=exp2(-j*ROPE_C)

// ---------------- repack fp32 [R][4096] -> packed fp16 [R/128][128 kb][128 r][32 c] ----------------
// Bank swizzle baked in: elem pos = r*32 + ((slot ^ ((r>>1)&3))<<3) + (c&7), slot = c>>3.
__global__ __launch_bounds__(256) void repack_x16(const float* __restrict__ src,
                                                  uint16_t* __restrict__ dh)
{
    const int p  = blockIdx.y;
    const int kb = blockIdx.x;
    const int tid = threadIdx.x;
    const int rr = tid >> 3;
    const int k4 = tid & 7;
    const int slot = k4 >> 1;
    const int so   = (k4 & 1) * 4;
    uint16_t* bh = dh + ((size_t)p * 128 + kb) * 4096;
    #pragma unroll
    for (int it = 0; it < 4; ++it) {
        const int r = it * 32 + rr;
        const float4 v = *reinterpret_cast<const float4*>(
            &src[((size_t)p * 128 + r) * 4096 + kb * 32 + k4 * 4]);
        float f[4] = {v.x, v.y, v.z, v.w};
        f16x4 h;
        #pragma unroll
        for (int e = 0; e < 4; ++e) h[e] = (f16_t)f[e];
        const int pos = r * 32 + ((slot ^ ((r >> 1) & 3)) << 3) + so;
        *reinterpret_cast<f16x4*>(&bh[pos]) = h;
    }
}

// combined wq|wk|wv -> 96-row-panel packed fp16: [64 pan][128 kb][96 r][32 c]
__global__ __launch_bounds__(256) void repack_w96_16(const float* __restrict__ wq,
                                                     const float* __restrict__ wk,
                                                     const float* __restrict__ wv,
                                                     uint16_t* __restrict__ dst)
{
    const int kb  = blockIdx.x;
    const int pan = blockIdx.y;
    const int tid = threadIdx.x;
    const int k4 = tid & 7;
    const int slot = k4 >> 1;
    const int so   = (k4 & 1) * 4;
    uint16_t* bh = dst + ((size_t)pan * 128 + kb) * 3072;
    #pragma unroll
    for (int it = 0; it < 3; ++it) {
        const int r = it * 32 + (tid >> 3);
        const int n = pan * 96 + r;
        const float* srow = (n < 4096) ? (wq + (size_t)n * 4096)
                          : (n < 5120) ? (wk + (size_t)(n - 4096) * 4096)
                                       : (wv + (size_t)(n - 5120) * 4096);
        const float4 v = *reinterpret_cast<const float4*>(srow + kb * 32 + k4 * 4);
        float f[4] = {v.x, v.y, v.z, v.w};
        f16x4 h;
        #pragma unroll
        for (int e = 0; e < 4; ++e) h[e] = (f16_t)f[e];
        const int pos = r * 32 + ((slot ^ ((r >> 1) & 3)) << 3) + so;
        *reinterpret_cast<f16x4*>(&bh[pos]) = h;
    }
}

// 128-row-panel fp16 repack (wo)
__global__ __launch_bounds__(256) void repack_h16(const float* __restrict__ src,
                                                  uint16_t* __restrict__ dh)
{
    const int p  = blockIdx.y;
    const int kb = blockIdx.x;
    const int tid = threadIdx.x;
    const int rr = tid >> 3;
    const int k4 = tid & 7;
    const int slot = k4 >> 1;
    const int so   = (k4 & 1) * 4;
    uint16_t* bh = dh + ((size_t)p * 128 + kb) * 4096;
    #pragma unroll
    for (int it = 0; it < 4; ++it) {
        const int r = it * 32 + rr;
        const float4 v = *reinterpret_cast<const float4*>(
            &src[((size_t)p * 128 + r) * 4096 + kb * 32 + k4 * 4]);
        float f[4] = {v.x, v.y, v.z, v.w};
        f16x4 h;
        #pragma unroll
        for (int e = 0; e < 4; ++e) h[e] = (f16_t)f[e];
        const int pos = r * 32 + ((slot ^ ((r >> 1) & 3)) << 3) + so;
        *reinterpret_cast<f16x4*>(&bh[pos]) = h;
    }
}

// ---------------- QKV GEMM: 128x192, fp16, BK=64, 2-buf, grid 512 (2 blocks/CU); fp16 outputs ----------------
__global__ __launch_bounds__(512) void gemm_qkv9(const uint16_t* __restrict__ xh,
                                                 const uint16_t* __restrict__ wqkv,
                                                 uint16_t* __restrict__ xq16,
                                                 uint16_t* __restrict__ xk16,
                                                 uint16_t* __restrict__ xv16)
{
    __shared__ char lds[2][40960];   // per buf: A 16K ([kk2][128r][32c]) | B 24K ([pan2][kk2][96r][32c])

    const int bid = blockIdx.x;
    const int swz = (bid & 7) * 64 + (bid >> 3);
    const int by = swz >> 5;
    const int bx = swz & 31;
    const int tid = threadIdx.x;
    const int w = tid >> 6, lane = tid & 63;
    const int wm = w >> 2, wn = w & 3;
    const int fr = lane & 15, s4 = lane >> 4;

    const uint16_t* sp[5];
    int dof[5];
    int stridec[5];
    #pragma unroll
    for (int i = 0; i < 5; ++i) {
        const int c = w + 8 * i;
        if (c < 16) {
            const int kk = c >> 3, inner = c & 7;
            sp[i] = xh + (size_t)by * 524288 + kk * 4096 + inner * 512 + lane * 8;
            dof[i] = c * 1024;
            stridec[i] = 8192;
        } else {
            const int cb = c - 16;
            const int pan = cb / 12, rem = cb % 12;
            const int kk = rem / 6, inner = rem % 6;
            sp[i] = wqkv + (size_t)(bx * 2 + pan) * 393216 + kk * 3072 + inner * 512 + lane * 8;
            dof[i] = 16384 + cb * 1024;
            stridec[i] = 6144;
        }
    }

    f32x4 acc[4][3] = {};

    #pragma unroll
    for (int i = 0; i < 5; ++i)
        __builtin_amdgcn_global_load_lds(
            (const __attribute__((address_space(1))) void*)(sp[i]),
            (__attribute__((address_space(3))) void*)(&lds[0][0] + dof[i]), 16, 0, 0);
    asm volatile("s_waitcnt vmcnt(0)" ::: "memory");
    __builtin_amdgcn_s_barrier();
    __builtin_amdgcn_sched_barrier(0);

    for (int t = 0; t < 64; ++t) {
        const char* b = &lds[t & 1][0];
        if (t + 1 < 64) {
            char* nb = &lds[(t + 1) & 1][0];
            #pragma unroll
            for (int i = 0; i < 5; ++i)
                __builtin_amdgcn_global_load_lds(
                    (const __attribute__((address_space(1))) void*)(sp[i] + (size_t)(t + 1) * stridec[i]),
                    (__attribute__((address_space(3))) void*)(nb + dof[i]), 16, 0, 0);
        }
        #pragma unroll
        for (int kk = 0; kk < 2; ++kk) {
            f16x8 fb[3];
            #pragma unroll
            for (int j = 0; j < 3; ++j) {
                const int cbp = wn * 48 + j * 16 + fr;
                const int pan = (cbp >= 96) ? 1 : 0;
                const int rb = cbp - pan * 96;
                fb[j] = *reinterpret_cast<const f16x8*>(
                    b + 16384 + pan * 12288 + kk * 6144 + rb * 64 + ((s4 ^ ((rb >> 1) & 3)) << 4));
            }
            #pragma unroll
            for (int ri = 0; ri < 4; ++ri) {
                const int rloc = wm * 64 + ri * 16 + fr;
                f16x8 fh = *reinterpret_cast<const f16x8*>(
                    b + kk * 8192 + rloc * 64 + ((s4 ^ ((rloc >> 1) & 3)) << 4));
                __builtin_amdgcn_s_setprio(1);
                #pragma unroll
                for (int j = 0; j < 3; ++j)
                    acc[ri][j] = __builtin_amdgcn_mfma_f32_16x16x32_f16(fh, fb[j], acc[ri][j], 0, 0, 0);
                __builtin_amdgcn_s_setprio(0);
            }
        }
        asm volatile("s_waitcnt vmcnt(0)" ::: "memory");
        __builtin_amdgcn_s_barrier();
        __builtin_amdgcn_sched_barrier(0);
    }

    const int r0 = by * 128 + wm * 64 + s4 * 4;
    const int c0 = bx * 192 + wn * 48 + fr;
    #pragma unroll
    for (int ri = 0; ri < 4; ++ri)
        #pragma unroll
        for (int j = 0; j < 3; ++j) {
            const int col = c0 + j * 16;
            #pragma unroll
            for (int rr = 0; rr < 4; ++rr) {
                const int row = r0 + ri * 16 + rr;
                const f16_t v = (f16_t)acc[ri][j][rr];
                uint16_t bits;
                __builtin_memcpy(&bits, &v, 2);
                if (col < 4096)      xq16[(size_t)row * 4096 + col] = bits;
                else if (col < 5120) xk16[(size_t)row * 1024 + (col - 4096)] = bits;
                else                 xv16[(size_t)row * 1024 + (col - 5120)] = bits;
            }
        }
}

// ---------------- Output GEMM: 256x128, fp16, BK=64, 2-buf, grid 256 (round-12 proven shape) ----------------
__global__ __launch_bounds__(512) void gemm_out8(const uint16_t* __restrict__ aoh,
                                                 const uint16_t* __restrict__ woh,
                                                 float* __restrict__ out)
{
    __shared__ char lds[2][49152];   // A 32K | B 16K ([kk2][128r][32c])

    const int bid = blockIdx.x;
    const int swz = (bid & 7) * 32 + (bid >> 3);
    const int by = swz >> 5;
    const int bx = swz & 31;
    const int tid = threadIdx.x;
    const int w = tid >> 6, lane = tid & 63;
    const int wm = w >> 2, wn = w & 3;
    const int fr = lane & 15, s4 = lane >> 4;

    const uint16_t* sp[6];
    int dof[6];
    #pragma unroll
    for (int i = 0; i < 6; ++i) {
        const int c = w + 8 * i;
        if (c < 32) {
            const int pan = c >> 4, sub = c & 15;
            sp[i] = aoh + (size_t)(2 * by + pan) * 524288 + sub * 512 + lane * 8;
            dof[i] = c * 1024;
        } else {
            sp[i] = woh + (size_t)bx * 524288 + (c - 32) * 512 + lane * 8;
            dof[i] = 32768 + (c - 32) * 1024;
        }
    }

    f32x4 acc[8][2] = {};

    #pragma unroll
    for (int i = 0; i < 6; ++i)
        __builtin_amdgcn_global_load_lds(
            (const __attribute__((address_space(1))) void*)(sp[i]),
            (__attribute__((address_space(3))) void*)(&lds[0][0] + dof[i]), 16, 0, 0);
    asm volatile("s_waitcnt vmcnt(0)" ::: "memory");
    __builtin_amdgcn_s_barrier();
    __builtin_amdgcn_sched_barrier(0);

    for (int t = 0; t < 64; ++t) {
        const char* b = &lds[t & 1][0];
        if (t + 1 < 64) {
            char* nb = &lds[(t + 1) & 1][0];
            #pragma unroll
            for (int i = 0; i < 6; ++i)
                __builtin_amdgcn_global_load_lds(
                    (const __attribute__((address_space(1))) void*)(sp[i] + (size_t)(t + 1) * 8192),
                    (__attribute__((address_space(3))) void*)(nb + dof[i]), 16, 0, 0);
        }
        #pragma unroll
        for (int kk = 0; kk < 2; ++kk) {
            f16x8 fb[2];
            #pragma unroll
            for (int j = 0; j < 2; ++j) {
                const int cbp = wn * 32 + j * 16 + fr;
                fb[j] = *reinterpret_cast<const f16x8*>(
                    b + 32768 + kk * 8192 + cbp * 64 + ((s4 ^ ((cbp >> 1) & 3)) << 4));
            }
            #pragma unroll
            for (int p = 0; p < 4; ++p) {
                f16x8 fh[2];
                #pragma unroll
                for (int f = 0; f < 2; ++f) {
                    const int rloc = p * 32 + f * 16 + fr;
                    fh[f] = *reinterpret_cast<const f16x8*>(
                        b + wm * 16384 + kk * 8192 + rloc * 64 + ((s4 ^ ((rloc >> 1) & 3)) << 4));
                }
                __builtin_amdgcn_s_setprio(1);
                #pragma unroll
                for (int f = 0; f < 2; ++f)
                    #pragma unroll
                    for (int j = 0; j < 2; ++j)
                        acc[p * 2 + f][j] = __builtin_amdgcn_mfma_f32_16x16x32_f16(fh[f], fb[j], acc[p * 2 + f][j], 0, 0, 0);
                __builtin_amdgcn_s_setprio(0);
            }
        }
        asm volatile("s_waitcnt vmcnt(0)" ::: "memory");
        __builtin_amdgcn_s_barrier();
        __builtin_amdgcn_sched_barrier(0);
    }

    const int r0 = by * 256 + wm * 128 + s4 * 4;
    const int c0 = bx * 128 + wn * 32 + fr;
    #pragma unroll
    for (int ri = 0; ri < 8; ++ri)
        #pragma unroll
        for (int j = 0; j < 2; ++j)
            #pragma unroll
            for (int rr = 0; rr < 4; ++rr)
                out[(size_t)(r0 + ri * 16 + rr) * 4096 + c0 + j * 16] = acc[ri][j][rr];
}

// ---------------- conv_kv: fp16 K/V in; rope applied to K here; fp16 swizzled tiles out ----------------
// Tile = 8192 uint16 (16 KB): K [32 kv][128 d] at 0, Vt [128 d][32 kv] at 4096.
__global__ __launch_bounds__(256) void conv_kv(const uint16_t* __restrict__ xk16,
                                               const uint16_t* __restrict__ xv16,
                                               uint16_t* __restrict__ kvg)
{
    __shared__ float V[32][129];
    const int t = blockIdx.x;
    const int h = blockIdx.y;
    const int tid = threadIdx.x;
    uint16_t* tile = kvg + ((size_t)(h * 64 + t)) * 8192;

    // stage V tile (fp16 -> float LDS for transpose)
    #pragma unroll
    for (int i = 0; i < 4; ++i) {
        const int v = i * 256 + tid;
        const int row = v >> 5, c4 = (v & 31) * 4;
        f16x4 hv = *reinterpret_cast<const f16x4*>(&xv16[(size_t)(t * 32 + row) * 1024 + h * 128 + c4]);
        #pragma unroll
        for (int e = 0; e < 4; ++e) V[row][c4 + e] = (float)hv[e];
    }

    // K: load fp16, rope in fp32, write swizzled fp16
    {
        const int r = tid >> 3;
        const int d0 = (tid & 7) * 16;
        const int pos_ = t * 32 + r;
        float f[16];
        const uint16_t* kr = &xk16[(size_t)pos_ * 1024 + h * 128 + d0];
        f16x8 k0 = *reinterpret_cast<const f16x8*>(kr);
        f16x8 k1 = *reinterpret_cast<const f16x8*>(kr + 8);
        #pragma unroll
        for (int e = 0; e < 8; ++e) { f[e] = (float)k0[e]; f[8 + e] = (float)k1[e]; }
        #pragma unroll
        for (int i = 0; i < 8; ++i) {
            const int j = (d0 >> 1) + i;
            const float invf = exp2f(-(float)j * ROPE_C);
            const float ang = (float)pos_ * invf;
            float sn, cs;
            __sincosf(ang, &sn, &cs);
            const float x1 = f[2 * i], x2 = f[2 * i + 1];
            f[2 * i]     = x1 * cs - x2 * sn;
            f[2 * i + 1] = x1 * sn + x2 * cs;
        }
        #pragma unroll
        for (int cc = 0; cc < 2; ++cc) {
            f16x8 hv;
            #pragma unroll
            for (int e = 0; e < 8; ++e) hv[e] = (f16_t)f[cc * 8 + e];
            const int c = (d0 >> 3) + cc;
            const int pos = r * 128 + ((c ^ (r & 15)) << 3);
            *reinterpret_cast<f16x8*>(&tile[pos]) = hv;
        }
    }
    __syncthreads();
    // V transpose -> fp16
    {
        const int d = tid >> 1;
        const int k0 = (tid & 1) * 16;
        float g[16];
        #pragma unroll
        for (int j = 0; j < 16; ++j) g[j] = V[k0 + j][d];
        #pragma unroll
        for (int cc = 0; cc < 2; ++cc) {
            f16x8 hv;
            #pragma unroll
            for (int e = 0; e < 8; ++e) hv[e] = (f16_t)g[cc * 8 + e];
            const int c = (k0 >> 3) + cc;
            const int pos = 4096 + d * 32 + ((c ^ (d & 3)) << 3);
            *reinterpret_cast<f16x8*>(&tile[pos]) = hv;
        }
    }
}

// ---------------- MFMA flash attention (fp16; rope+scale on Q in-register; defer-max; fp16 epilogue) ----------------
__device__ __forceinline__ uint cvtpkh(float lo, float hi) {
    uint r;
    asm("v_cvt_pkrtz_f16_f32 %0, %1, %2" : "=v"(r) : "v"(lo), "v"(hi));
    return r;
}
__device__ __forceinline__ void permswap(uint& a, uint& b) {
    asm("v_permlane32_swap_b32 %0, %1" : "+v"(a), "+v"(b));
}
__device__ __forceinline__ f16x8 pack4h(uint w0, uint w1, uint w2, uint w3) {
    union { uint u[4]; f16x8 v; } t;
    t.u[0] = w0; t.u[1] = w1; t.u[2] = w2; t.u[3] = w3;
    return t.v;
}

__global__ __launch_bounds__(512, 2) void attn_mfma(const uint16_t* __restrict__ xq16,
                                                    const uint16_t* __restrict__ kvg,
                                                    uint16_t* __restrict__ aoh)
{
    __shared__ char lds[2][16384];

    const int b = blockIdx.x;
    const int kvh = b & 7;
    const int r = b >> 3;
    const int h = kvh * 4 + (r & 3);
    const int q0 = (r >> 2) * 256;
    const int tid = threadIdx.x;
    const int w = tid >> 6;
    const int lane = tid & 63;
    const int ln31 = lane & 31;
    const int hi = lane >> 5;

    const int q = q0 + w * 32 + ln31;
    const uint16_t* qrow = xq16 + (size_t)q * 4096 + h * 128;
    f16x8 Qh[8];
    #pragma unroll
    for (int ks = 0; ks < 8; ++ks) {
        const int dbase = ks * 16 + hi * 8;
        f16x8 raw = *reinterpret_cast<const f16x8*>(qrow + dbase);
        float f[8];
        #pragma unroll
        for (int e = 0; e < 8; ++e) f[e] = (float)raw[e];
        #pragma unroll
        for (int i = 0; i < 4; ++i) {
            const int j = (dbase >> 1) + i;
            const float invf = exp2f(-(float)j * ROPE_C);
            const float ang = (float)q * invf;
            float sn, cs;
            __sincosf(ang, &sn, &cs);
            const float x1 = f[2 * i], x2 = f[2 * i + 1];
            f[2 * i]     = (x1 * cs - x2 * sn) * 0.08838834764831845f;
            f[2 * i + 1] = (x1 * sn + x2 * cs) * 0.08838834764831845f;
        }
        #pragma unroll
        for (int e = 0; e < 8; ++e) Qh[ks][e] = (f16_t)f[e];
    }

    const char* gkv = (const char*)kvg + (size_t)kvh * 64 * 16384;

    f32x16 oacc[4] = {{}, {}, {}, {}};
    float m = -3.0e38f, l = 0.f;

    {
        #pragma unroll
        for (int i = 0; i < 2; ++i) {
            const int chunk = i * 8 + w;
            __builtin_amdgcn_global_load_lds(
                (const __attribute__((address_space(1))) void*)(gkv + chunk * 1024 + lane * 16),
                (__attribute__((address_space(3))) void*)(&lds[0][chunk * 1024]),
                16, 0, 0);
        }
    }

    for (int t = 0; t < 64; ++t) {
        __syncthreads();
        if (t + 1 < 64) {
            const char* g = gkv + (size_t)(t + 1) * 16384;
            const int buf = (t + 1) & 1;
            #pragma unroll
            for (int i = 0; i < 2; ++i) {
                const int chunk = i * 8 + w;
                __builtin_amdgcn_global_load_lds(
                    (const __attribute__((address_space(1))) void*)(g + chunk * 1024 + lane * 16),
                    (__attribute__((address_space(3))) void*)(&lds[buf][chunk * 1024]),
                    16, 0, 0);
            }
        }
        const int cur = t & 1;
        const char* Kf = lds[cur];
        const char* Vf = lds[cur] + 8192;

        f32x16 s0 = {}, s1 = {};
        __builtin_amdgcn_s_setprio(1);
        #pragma unroll
        for (int ks = 0; ks < 8; ++ks) {
            const int byt = ln31 * 256 + ((ks * 32 + hi * 16) ^ ((ln31 & 15) << 4));
            f16x8 a = *reinterpret_cast<const f16x8*>(Kf + byt);
            if (ks & 1) s1 = __builtin_amdgcn_mfma_f32_32x32x16_f16(a, Qh[ks], s1, 0, 0, 0);
            else        s0 = __builtin_amdgcn_mfma_f32_32x32x16_f16(a, Qh[ks], s0, 0, 0, 0);
        }
        __builtin_amdgcn_s_setprio(0);
        f32x16 s = s0 + s1;

        float pmax = s[0];
        #pragma unroll
        for (int jj = 1; jj < 16; ++jj) pmax = fmaxf(pmax, s[jj]);
        pmax = fmaxf(pmax, __shfl_xor(pmax, 32));
        if (!__all(pmax - m <= 8.0f)) {
            const float mnew = fmaxf(m, pmax);
            const float corr = __expf(m - mnew);
            l *= corr;
            #pragma unroll
            for (int dt = 0; dt < 4; ++dt) oacc[dt] *= corr;
            m = mnew;
        }
        float psum = 0.f;
        #pragma unroll
        for (int jj = 0; jj < 16; ++jj) {
            float pv = __expf(s[jj] - m);
            s[jj] = pv;
            psum += pv;
        }
        psum += __shfl_xor(psum, 32);
        l += psum;

        #pragma unroll
        for (int ks = 0; ks < 2; ++ks) {
            const int b0 = ks * 8;
            uint wa = cvtpkh(s[b0 + 0], s[b0 + 1]);
            uint wb = cvtpkh(s[b0 + 2], s[b0 + 3]);
            uint wc = cvtpkh(s[b0 + 4], s[b0 + 5]);
            uint wd = cvtpkh(s[b0 + 6], s[b0 + 7]);
            permswap(wa, wc); permswap(wb, wd);
            f16x8 Pf = pack4h(wa, wb, wc, wd);
            __builtin_amdgcn_s_setprio(1);
            #pragma unroll
            for (int dt = 0; dt < 4; ++dt) {
                const int row = dt * 32 + ln31;
                const int byt = row * 64 + ((ks * 32 + hi * 16) ^ ((row & 3) << 4));
                f16x8 vh = *reinterpret_cast<const f16x8*>(Vf + byt);
                oacc[dt] = __builtin_amdgcn_mfma_f32_32x32x16_f16(vh, Pf, oacc[dt], 0, 0, 0);
            }
            __builtin_amdgcn_s_setprio(0);
        }
    }

    // ---- epilogue: O -> fp16, packed layout for gemm_out8 ----
    const float invl = 1.0f / l;
    const int p   = q >> 7;
    const int rr_ = q & 127;
    const int rsw = (rr_ >> 1) & 3;
    #pragma unroll
    for (int dt = 0; dt < 4; ++dt) {
        const int kb = h * 4 + dt;
        uint16_t* bh = aoh + ((size_t)p * 128 + kb) * 4096;
        #pragma unroll
        for (int g4 = 0; g4 < 4; ++g4) {
            f16x4 hv;
            #pragma unroll
            for (int e = 0; e < 4; ++e)
                hv[e] = (f16_t)(oacc[dt][g4 * 4 + e] * invl);
            const int pos = rr_ * 32 + ((g4 ^ rsw) << 3) + 4 * hi;
            *reinterpret_cast<f16x4*>(&bh[pos]) = hv;
        }
    }
}

extern "C" void kernel_launch(void* const* d_in, const int* in_sizes, int n_in,
                              void* d_out, int out_size, void* d_ws, size_t ws_size,
                              hipStream_t stream)
{
    const float* x  = (const float*)d_in[0];
    const float* wq = (const float*)d_in[1];
    const float* wk = (const float*)d_in[2];
    const float* wv = (const float*)d_in[3];
    const float* wo = (const float*)d_in[4];
    float* out = (float*)d_out;

    float* ws = (float*)d_ws;
    uint16_t* xq16 = (uint16_t*)ws;                // fp16 Q [2048][4096] (16 MB)
    uint16_t* kvg  = (uint16_t*)(ws + 8388608);    // fp16 K/V tiles (8.4 MB)
    uint16_t* xk16 = (uint16_t*)(ws + 12582912);   // fp16 K [2048][1024] (4 MB)
    uint16_t* xv16 = (uint16_t*)(ws + 14680064);   // fp16 V [2048][1024] (4 MB)
    uint16_t* aoh  = (uint16_t*)(ws + 12582912);   // reuses xk slot after conv_kv
    uint16_t* xh   = (uint16_t*)(ws + 20971520);   // fp16 packed x
    uint16_t* wqkv = (uint16_t*)(ws + 29360128);   // fp16 packed wq|wk|wv
    uint16_t* woh  = (uint16_t*)(ws + 41943040);   // fp16 packed wo

    dim3 blk(256);
    repack_x16   <<<dim3(128, 16), blk, 0, stream>>>(x, xh);
    repack_w96_16<<<dim3(128, 64), blk, 0, stream>>>(wq, wk, wv, wqkv);
    gemm_qkv9    <<<dim3(512), dim3(512), 0, stream>>>(xh, wqkv, xq16, xk16, xv16);
    repack_h16   <<<dim3(128, 32), blk, 0, stream>>>(wo, woh);
    conv_kv      <<<dim3(64, 8), blk, 0, stream>>>(xk16, xv16, kvg);
    attn_mfma    <<<dim3(256), dim3(512), 0, stream>>>(xq16, kvg, aoh);
    gemm_out8    <<<dim3(256), dim3(512), 0, stream>>>(aoh, woh, out);
}

// Round 15
// 350.742 us; speedup vs baseline: 1.1010x; 1.0443x over previous
//
#include <hip/hip_runtime.h>
#include <hip/hip_bf16.h>

typedef _Float16 f16_t;
typedef unsigned int uint;
typedef __attribute__((ext_vector_type(8))) _Float16 f16x8;
typedef __attribute__((ext_vector_type(4))) _Float16 f16x4;
typedef __attribute__((ext_vector_type(4))) float f32x4;
typedef __attribute__((ext_vector_type(16))) float f32x16;

#define ROPE_C (13.287712379549449f / 64.0f)   // log2(10000)/64; invf(j)=exp2(-j*ROPE_C)

// ---------------- repack fp32 [R][4096] -> packed fp16 [R/128][128 kb][128 r][32 c] ----------------
__global__ __launch_bounds__(256) void repack_x16(const float* __restrict__ src,
                                                  uint16_t* __restrict__ dh)
{
    const int p  = blockIdx.y;
    const int kb = blockIdx.x;
    const int tid = threadIdx.x;
    const int rr = tid >> 3;
    const int k4 = tid & 7;
    const int slot = k4 >> 1;
    const int so   = (k4 & 1) * 4;
    uint16_t* bh = dh + ((size_t)p * 128 + kb) * 4096;
    #pragma unroll
    for (int it = 0; it < 4; ++it) {
        const int r = it * 32 + rr;
        const float4 v = *reinterpret_cast<const float4*>(
            &src[((size_t)p * 128 + r) * 4096 + kb * 32 + k4 * 4]);
        float f[4] = {v.x, v.y, v.z, v.w};
        f16x4 h;
        #pragma unroll
        for (int e = 0; e < 4; ++e) h[e] = (f16_t)f[e];
        const int pos = r * 32 + ((slot ^ ((r >> 1) & 3)) << 3) + so;
        *reinterpret_cast<f16x4*>(&bh[pos]) = h;
    }
}

// combined wq|wk|wv -> 96-row-panel packed fp16: [64 pan][128 kb][96 r][32 c]
__global__ __launch_bounds__(256) void repack_w96_16(const float* __restrict__ wq,
                                                     const float* __restrict__ wk,
                                                     const float* __restrict__ wv,
                                                     uint16_t* __restrict__ dst)
{
    const int kb  = blockIdx.x;
    const int pan = blockIdx.y;
    const int tid = threadIdx.x;
    const int k4 = tid & 7;
    const int slot = k4 >> 1;
    const int so   = (k4 & 1) * 4;
    uint16_t* bh = dst + ((size_t)pan * 128 + kb) * 3072;
    #pragma unroll
    for (int it = 0; it < 3; ++it) {
        const int r = it * 32 + (tid >> 3);
        const int n = pan * 96 + r;
        const float* srow = (n < 4096) ? (wq + (size_t)n * 4096)
                          : (n < 5120) ? (wk + (size_t)(n - 4096) * 4096)
                                       : (wv + (size_t)(n - 5120) * 4096);
        const float4 v = *reinterpret_cast<const float4*>(srow + kb * 32 + k4 * 4);
        float f[4] = {v.x, v.y, v.z, v.w};
        f16x4 h;
        #pragma unroll
        for (int e = 0; e < 4; ++e) h[e] = (f16_t)f[e];
        const int pos = r * 32 + ((slot ^ ((r >> 1) & 3)) << 3) + so;
        *reinterpret_cast<f16x4*>(&bh[pos]) = h;
    }
}

// ---------------- QKV GEMM: 128x192, fp16, BK=64, 2-buf, grid 512; 2-D XCD partition ----------------
__global__ __launch_bounds__(512) void gemm_qkv9(const uint16_t* __restrict__ xh,
                                                 const uint16_t* __restrict__ wqkv,
                                                 uint16_t* __restrict__ xq16,
                                                 uint16_t* __restrict__ xk16,
                                                 uint16_t* __restrict__ xv16)
{
    __shared__ char lds[2][40960];   // per buf: A 16K ([kk2][128r][32c]) | B 24K ([pan2][kk2][96r][32c])

    const int bid = blockIdx.x;
    const int xcd = bid & 7;
    const int i_  = bid >> 3;                      // 0..63
    const int by = (xcd & 1) * 8 + (i_ & 7);       // 8by x 8bx region per XCD (20 MB footprint)
    const int bx = (xcd >> 1) * 8 + (i_ >> 3);
    const int tid = threadIdx.x;
    const int w = tid >> 6, lane = tid & 63;
    const int wm = w >> 2, wn = w & 3;
    const int fr = lane & 15, s4 = lane >> 4;

    const uint16_t* sp[5];
    int dof[5];
    int stridec[5];
    #pragma unroll
    for (int i = 0; i < 5; ++i) {
        const int c = w + 8 * i;
        if (c < 16) {
            const int kk = c >> 3, inner = c & 7;
            sp[i] = xh + (size_t)by * 524288 + kk * 4096 + inner * 512 + lane * 8;
            dof[i] = c * 1024;
            stridec[i] = 8192;
        } else {
            const int cb = c - 16;
            const int pan = cb / 12, rem = cb % 12;
            const int kk = rem / 6, inner = rem % 6;
            sp[i] = wqkv + (size_t)(bx * 2 + pan) * 393216 + kk * 3072 + inner * 512 + lane * 8;
            dof[i] = 16384 + cb * 1024;
            stridec[i] = 6144;
        }
    }

    f32x4 acc[4][3] = {};

    #pragma unroll
    for (int i = 0; i < 5; ++i)
        __builtin_amdgcn_global_load_lds(
            (const __attribute__((address_space(1))) void*)(sp[i]),
            (__attribute__((address_space(3))) void*)(&lds[0][0] + dof[i]), 16, 0, 0);
    asm volatile("s_waitcnt vmcnt(0)" ::: "memory");
    __builtin_amdgcn_s_barrier();
    __builtin_amdgcn_sched_barrier(0);

    for (int t = 0; t < 64; ++t) {
        const char* b = &lds[t & 1][0];
        if (t + 1 < 64) {
            char* nb = &lds[(t + 1) & 1][0];
            #pragma unroll
            for (int i = 0; i < 5; ++i)
                __builtin_amdgcn_global_load_lds(
                    (const __attribute__((address_space(1))) void*)(sp[i] + (size_t)(t + 1) * stridec[i]),
                    (__attribute__((address_space(3))) void*)(nb + dof[i]), 16, 0, 0);
        }
        #pragma unroll
        for (int kk = 0; kk < 2; ++kk) {
            f16x8 fb[3];
            #pragma unroll
            for (int j = 0; j < 3; ++j) {
                const int cbp = wn * 48 + j * 16 + fr;
                const int pan = (cbp >= 96) ? 1 : 0;
                const int rb = cbp - pan * 96;
                fb[j] = *reinterpret_cast<const f16x8*>(
                    b + 16384 + pan * 12288 + kk * 6144 + rb * 64 + ((s4 ^ ((rb >> 1) & 3)) << 4));
            }
            #pragma unroll
            for (int ri = 0; ri < 4; ++ri) {
                const int rloc = wm * 64 + ri * 16 + fr;
                f16x8 fh = *reinterpret_cast<const f16x8*>(
                    b + kk * 8192 + rloc * 64 + ((s4 ^ ((rloc >> 1) & 3)) << 4));
                __builtin_amdgcn_s_setprio(1);
                #pragma unroll
                for (int j = 0; j < 3; ++j)
                    acc[ri][j] = __builtin_amdgcn_mfma_f32_16x16x32_f16(fh, fb[j], acc[ri][j], 0, 0, 0);
                __builtin_amdgcn_s_setprio(0);
            }
        }
        asm volatile("s_waitcnt vmcnt(0)" ::: "memory");
        __builtin_amdgcn_s_barrier();
        __builtin_amdgcn_sched_barrier(0);
    }

    const int r0 = by * 128 + wm * 64 + s4 * 4;
    const int c0 = bx * 192 + wn * 48 + fr;
    #pragma unroll
    for (int ri = 0; ri < 4; ++ri)
        #pragma unroll
        for (int j = 0; j < 3; ++j) {
            const int col = c0 + j * 16;
            #pragma unroll
            for (int rr = 0; rr < 4; ++rr) {
                const int row = r0 + ri * 16 + rr;
                const f16_t v = (f16_t)acc[ri][j][rr];
                uint16_t bits;
                __builtin_memcpy(&bits, &v, 2);
                if (col < 4096)      xq16[(size_t)row * 4096 + col] = bits;
                else if (col < 5120) xk16[(size_t)row * 1024 + (col - 4096)] = bits;
                else                 xv16[(size_t)row * 1024 + (col - 5120)] = bits;
            }
        }
}

// ---------------- Output GEMM: 256x128, fp16, BK=64, 2-buf, grid 256; 2-D XCD partition ----------------
__global__ __launch_bounds__(512) void gemm_out8(const uint16_t* __restrict__ aoh,
                                                 const uint16_t* __restrict__ woh,
                                                 float* __restrict__ out)
{
    __shared__ char lds[2][49152];   // A 32K | B 16K ([kk2][128r][32c])

    const int bid = blockIdx.x;
    const int xcd = bid & 7;
    const int i_  = bid >> 3;                      // 0..31
    const int by = (xcd & 1) * 4 + (i_ & 3);       // 4by x 8bx region per XCD (16 MB footprint)
    const int bx = (xcd >> 1) * 8 + (i_ >> 2);
    const int tid = threadIdx.x;
    const int w = tid >> 6, lane = tid & 63;
    const int wm = w >> 2, wn = w & 3;
    const int fr = lane & 15, s4 = lane >> 4;

    const uint16_t* sp[6];
    int dof[6];
    #pragma unroll
    for (int i = 0; i < 6; ++i) {
        const int c = w + 8 * i;
        if (c < 32) {
            const int pan = c >> 4, sub = c & 15;
            sp[i] = aoh + (size_t)(2 * by + pan) * 524288 + sub * 512 + lane * 8;
            dof[i] = c * 1024;
        } else {
            sp[i] = woh + (size_t)bx * 524288 + (c - 32) * 512 + lane * 8;
            dof[i] = 32768 + (c - 32) * 1024;
        }
    }

    f32x4 acc[8][2] = {};

    #pragma unroll
    for (int i = 0; i < 6; ++i)
        __builtin_amdgcn_global_load_lds(
            (const __attribute__((address_space(1))) void*)(sp[i]),
            (__attribute__((address_space(3))) void*)(&lds[0][0] + dof[i]), 16, 0, 0);
    asm volatile("s_waitcnt vmcnt(0)" ::: "memory");
    __builtin_amdgcn_s_barrier();
    __builtin_amdgcn_sched_barrier(0);

    for (int t = 0; t < 64; ++t) {
        const char* b = &lds[t & 1][0];
        if (t + 1 < 64) {
            char* nb = &lds[(t + 1) & 1][0];
            #pragma unroll
            for (int i = 0; i < 6; ++i)
                __builtin_amdgcn_global_load_lds(
                    (const __attribute__((address_space(1))) void*)(sp[i] + (size_t)(t + 1) * 8192),
                    (__attribute__((address_space(3))) void*)(nb + dof[i]), 16, 0, 0);
        }
        #pragma unroll
        for (int kk = 0; kk < 2; ++kk) {
            f16x8 fb[2];
            #pragma unroll
            for (int j = 0; j < 2; ++j) {
                const int cbp = wn * 32 + j * 16 + fr;
                fb[j] = *reinterpret_cast<const f16x8*>(
                    b + 32768 + kk * 8192 + cbp * 64 + ((s4 ^ ((cbp >> 1) & 3)) << 4));
            }
            #pragma unroll
            for (int p = 0; p < 4; ++p) {
                f16x8 fh[2];
                #pragma unroll
                for (int f = 0; f < 2; ++f) {
                    const int rloc = p * 32 + f * 16 + fr;
                    fh[f] = *reinterpret_cast<const f16x8*>(
                        b + wm * 16384 + kk * 8192 + rloc * 64 + ((s4 ^ ((rloc >> 1) & 3)) << 4));
                }
                __builtin_amdgcn_s_setprio(1);
                #pragma unroll
                for (int f = 0; f < 2; ++f)
                    #pragma unroll
                    for (int j = 0; j < 2; ++j)
                        acc[p * 2 + f][j] = __builtin_amdgcn_mfma_f32_16x16x32_f16(fh[f], fb[j], acc[p * 2 + f][j], 0, 0, 0);
                __builtin_amdgcn_s_setprio(0);
            }
        }
        asm volatile("s_waitcnt vmcnt(0)" ::: "memory");
        __builtin_amdgcn_s_barrier();
        __builtin_amdgcn_sched_barrier(0);
    }

    const int r0 = by * 256 + wm * 128 + s4 * 4;
    const int c0 = bx * 128 + wn * 32 + fr;
    #pragma unroll
    for (int ri = 0; ri < 8; ++ri)
        #pragma unroll
        for (int j = 0; j < 2; ++j)
            #pragma unroll
            for (int rr = 0; rr < 4; ++rr)
                out[(size_t)(r0 + ri * 16 + rr) * 4096 + c0 + j * 16] = acc[ri][j][rr];
}

// ---------------- conv_kv: fp16 K/V in; rope applied to K here; fp16 swizzled tiles out ----------------
__global__ __launch_bounds__(256) void conv_kv(const uint16_t* __restrict__ xk16,
                                               const uint16_t* __restrict__ xv16,
                                               uint16_t* __restrict__ kvg)
{
    __shared__ float V[32][129];
    const int t = blockIdx.x;
    const int h = blockIdx.y;
    const int tid = threadIdx.x;
    uint16_t* tile = kvg + ((size_t)(h * 64 + t)) * 8192;

    #pragma unroll
    for (int i = 0; i < 4; ++i) {
        const int v = i * 256 + tid;
        const int row = v >> 5, c4 = (v & 31) * 4;
        f16x4 hv = *reinterpret_cast<const f16x4*>(&xv16[(size_t)(t * 32 + row) * 1024 + h * 128 + c4]);
        #pragma unroll
        for (int e = 0; e < 4; ++e) V[row][c4 + e] = (float)hv[e];
    }

    {
        const int r = tid >> 3;
        const int d0 = (tid & 7) * 16;
        const int pos_ = t * 32 + r;
        float f[16];
        const uint16_t* kr = &xk16[(size_t)pos_ * 1024 + h * 128 + d0];
        f16x8 k0 = *reinterpret_cast<const f16x8*>(kr);
        f16x8 k1 = *reinterpret_cast<const f16x8*>(kr + 8);
        #pragma unroll
        for (int e = 0; e < 8; ++e) { f[e] = (float)k0[e]; f[8 + e] = (float)k1[e]; }
        #pragma unroll
        for (int i = 0; i < 8; ++i) {
            const int j = (d0 >> 1) + i;
            const float invf = exp2f(-(float)j * ROPE_C);
            const float ang = (float)pos_ * invf;
            float sn, cs;
            __sincosf(ang, &sn, &cs);
            const float x1 = f[2 * i], x2 = f[2 * i + 1];
            f[2 * i]     = x1 * cs - x2 * sn;
            f[2 * i + 1] = x1 * sn + x2 * cs;
        }
        #pragma unroll
        for (int cc = 0; cc < 2; ++cc) {
            f16x8 hv;
            #pragma unroll
            for (int e = 0; e < 8; ++e) hv[e] = (f16_t)f[cc * 8 + e];
            const int c = (d0 >> 3) + cc;
            const int pos = r * 128 + ((c ^ (r & 15)) << 3);
            *reinterpret_cast<f16x8*>(&tile[pos]) = hv;
        }
    }
    __syncthreads();
    {
        const int d = tid >> 1;
        const int k0 = (tid & 1) * 16;
        float g[16];
        #pragma unroll
        for (int j = 0; j < 16; ++j) g[j] = V[k0 + j][d];
        #pragma unroll
        for (int cc = 0; cc < 2; ++cc) {
            f16x8 hv;
            #pragma unroll
            for (int e = 0; e < 8; ++e) hv[e] = (f16_t)g[cc * 8 + e];
            const int c = (k0 >> 3) + cc;
            const int pos = 4096 + d * 32 + ((c ^ (d & 3)) << 3);
            *reinterpret_cast<f16x8*>(&tile[pos]) = hv;
        }
    }
}

// ---------------- merged kernel: attn (blocks 0..255) + wo repack (blocks 256..4351) ----------------
__device__ __forceinline__ uint cvtpkh(float lo, float hi) {
    uint r;
    asm("v_cvt_pkrtz_f16_f32 %0, %1, %2" : "=v"(r) : "v"(lo), "v"(hi));
    return r;
}
__device__ __forceinline__ void permswap(uint& a, uint& b) {
    asm("v_permlane32_swap_b32 %0, %1" : "+v"(a), "+v"(b));
}
__device__ __forceinline__ f16x8 pack4h(uint w0, uint w1, uint w2, uint w3) {
    union { uint u[4]; f16x8 v; } t;
    t.u[0] = w0; t.u[1] = w1; t.u[2] = w2; t.u[3] = w3;
    return t.v;
}

__global__ __launch_bounds__(512, 2) void attn_mfma(const uint16_t* __restrict__ xq16,
                                                    const uint16_t* __restrict__ kvg,
                                                    uint16_t* __restrict__ aoh,
                                                    const float* __restrict__ wo,
                                                    uint16_t* __restrict__ woh)
{
    __shared__ char lds[2][16384];

    if (blockIdx.x >= 256) {
        // ---- wo repack path: [32 pan][128 kb][128 r][32 c] fp16 packed ----
        const int rid = blockIdx.x - 256;          // 0..4095
        const int p  = rid >> 7;
        const int kb = rid & 127;
        const int tid = threadIdx.x;
        const int t2 = tid & 255;
        const int half = tid >> 8;
        const int rr = t2 >> 3;
        const int k4 = t2 & 7;
        const int slot = k4 >> 1;
        const int so   = (k4 & 1) * 4;
        uint16_t* bh = woh + ((size_t)p * 128 + kb) * 4096;
        #pragma unroll
        for (int it = 0; it < 2; ++it) {
            const int r = (half * 2 + it) * 32 + rr;
            const float4 v = *reinterpret_cast<const float4*>(
                &wo[((size_t)p * 128 + r) * 4096 + kb * 32 + k4 * 4]);
            float f[4] = {v.x, v.y, v.z, v.w};
            f16x4 h;
            #pragma unroll
            for (int e = 0; e < 4; ++e) h[e] = (f16_t)f[e];
            const int pos = r * 32 + ((slot ^ ((r >> 1) & 3)) << 3) + so;
            *reinterpret_cast<f16x4*>(&bh[pos]) = h;
        }
        return;
    }

    const int b = blockIdx.x;
    const int kvh = b & 7;
    const int r = b >> 3;
    const int h = kvh * 4 + (r & 3);
    const int q0 = (r >> 2) * 256;
    const int tid = threadIdx.x;
    const int w = tid >> 6;
    const int lane = tid & 63;
    const int ln31 = lane & 31;
    const int hi = lane >> 5;

    const int q = q0 + w * 32 + ln31;
    const uint16_t* qrow = xq16 + (size_t)q * 4096 + h * 128;
    f16x8 Qh[8];
    #pragma unroll
    for (int ks = 0; ks < 8; ++ks) {
        const int dbase = ks * 16 + hi * 8;
        f16x8 raw = *reinterpret_cast<const f16x8*>(qrow + dbase);
        float f[8];
        #pragma unroll
        for (int e = 0; e < 8; ++e) f[e] = (float)raw[e];
        #pragma unroll
        for (int i = 0; i < 4; ++i) {
            const int j = (dbase >> 1) + i;
            const float invf = exp2f(-(float)j * ROPE_C);
            const float ang = (float)q * invf;
            float sn, cs;
            __sincosf(ang, &sn, &cs);
            const float x1 = f[2 * i], x2 = f[2 * i + 1];
            f[2 * i]     = (x1 * cs - x2 * sn) * 0.08838834764831845f;
            f[2 * i + 1] = (x1 * sn + x2 * cs) * 0.08838834764831845f;
        }
        #pragma unroll
        for (int e = 0; e < 8; ++e) Qh[ks][e] = (f16_t)f[e];
    }

    const char* gkv = (const char*)kvg + (size_t)kvh * 64 * 16384;

    f32x16 oacc[4] = {{}, {}, {}, {}};
    float m = -3.0e38f, l = 0.f;

    {
        #pragma unroll
        for (int i = 0; i < 2; ++i) {
            const int chunk = i * 8 + w;
            __builtin_amdgcn_global_load_lds(
                (const __attribute__((address_space(1))) void*)(gkv + chunk * 1024 + lane * 16),
                (__attribute__((address_space(3))) void*)(&lds[0][chunk * 1024]),
                16, 0, 0);
        }
    }

    for (int t = 0; t < 64; ++t) {
        __syncthreads();
        if (t + 1 < 64) {
            const char* g = gkv + (size_t)(t + 1) * 16384;
            const int buf = (t + 1) & 1;
            #pragma unroll
            for (int i = 0; i < 2; ++i) {
                const int chunk = i * 8 + w;
                __builtin_amdgcn_global_load_lds(
                    (const __attribute__((address_space(1))) void*)(g + chunk * 1024 + lane * 16),
                    (__attribute__((address_space(3))) void*)(&lds[buf][chunk * 1024]),
                    16, 0, 0);
            }
        }
        const int cur = t & 1;
        const char* Kf = lds[cur];
        const char* Vf = lds[cur] + 8192;

        f32x16 s0 = {}, s1 = {};
        __builtin_amdgcn_s_setprio(1);
        #pragma unroll
        for (int ks = 0; ks < 8; ++ks) {
            const int byt = ln31 * 256 + ((ks * 32 + hi * 16) ^ ((ln31 & 15) << 4));
            f16x8 a = *reinterpret_cast<const f16x8*>(Kf + byt);
            if (ks & 1) s1 = __builtin_amdgcn_mfma_f32_32x32x16_f16(a, Qh[ks], s1, 0, 0, 0);
            else        s0 = __builtin_amdgcn_mfma_f32_32x32x16_f16(a, Qh[ks], s0, 0, 0, 0);
        }
        __builtin_amdgcn_s_setprio(0);
        f32x16 s = s0 + s1;

        float pmax = s[0];
        #pragma unroll
        for (int jj = 1; jj < 16; ++jj) pmax = fmaxf(pmax, s[jj]);
        pmax = fmaxf(pmax, __shfl_xor(pmax, 32));
        if (!__all(pmax - m <= 8.0f)) {
            const float mnew = fmaxf(m, pmax);
            const float corr = __expf(m - mnew);
            l *= corr;
            #pragma unroll
            for (int dt = 0; dt < 4; ++dt) oacc[dt] *= corr;
            m = mnew;
        }
        float psum = 0.f;
        #pragma unroll
        for (int jj = 0; jj < 16; ++jj) {
            float pv = __expf(s[jj] - m);
            s[jj] = pv;
            psum += pv;
        }
        psum += __shfl_xor(psum, 32);
        l += psum;

        #pragma unroll
        for (int ks = 0; ks < 2; ++ks) {
            const int b0 = ks * 8;
            uint wa = cvtpkh(s[b0 + 0], s[b0 + 1]);
            uint wb = cvtpkh(s[b0 + 2], s[b0 + 3]);
            uint wc = cvtpkh(s[b0 + 4], s[b0 + 5]);
            uint wd = cvtpkh(s[b0 + 6], s[b0 + 7]);
            permswap(wa, wc); permswap(wb, wd);
            f16x8 Pf = pack4h(wa, wb, wc, wd);
            __builtin_amdgcn_s_setprio(1);
            #pragma unroll
            for (int dt = 0; dt < 4; ++dt) {
                const int row = dt * 32 + ln31;
                const int byt = row * 64 + ((ks * 32 + hi * 16) ^ ((row & 3) << 4));
                f16x8 vh = *reinterpret_cast<const f16x8*>(Vf + byt);
                oacc[dt] = __builtin_amdgcn_mfma_f32_32x32x16_f16(vh, Pf, oacc[dt], 0, 0, 0);
            }
            __builtin_amdgcn_s_setprio(0);
        }
    }

    const float invl = 1.0f / l;
    const int p   = q >> 7;
    const int rr_ = q & 127;
    const int rsw = (rr_ >> 1) & 3;
    #pragma unroll
    for (int dt = 0; dt < 4; ++dt) {
        const int kb = h * 4 + dt;
        uint16_t* bh = aoh + ((size_t)p * 128 + kb) * 4096;
        #pragma unroll
        for (int g4 = 0; g4 < 4; ++g4) {
            f16x4 hv;
            #pragma unroll
            for (int e = 0; e < 4; ++e)
                hv[e] = (f16_t)(oacc[dt][g4 * 4 + e] * invl);
            const int pos = rr_ * 32 + ((g4 ^ rsw) << 3) + 4 * hi;
            *reinterpret_cast<f16x4*>(&bh[pos]) = hv;
        }
    }
}

extern "C" void kernel_launch(void* const* d_in, const int* in_sizes, int n_in,
                              void* d_out, int out_size, void* d_ws, size_t ws_size,
                              hipStream_t stream)
{
    const float* x  = (const float*)d_in[0];
    const float* wq = (const float*)d_in[1];
    const float* wk = (const float*)d_in[2];
    const float* wv = (const float*)d_in[3];
    const float* wo = (const float*)d_in[4];
    float* out = (float*)d_out;

    float* ws = (float*)d_ws;
    uint16_t* xq16 = (uint16_t*)ws;                // fp16 Q [2048][4096] (16 MB)
    uint16_t* kvg  = (uint16_t*)(ws + 8388608);    // fp16 K/V tiles (8.4 MB)
    uint16_t* xk16 = (uint16_t*)(ws + 12582912);   // fp16 K [2048][1024]
    uint16_t* xv16 = (uint16_t*)(ws + 14680064);   // fp16 V [2048][1024]
    uint16_t* aoh  = (uint16_t*)(ws + 12582912);   // reuses xk slot after conv_kv
    uint16_t* xh   = (uint16_t*)(ws + 20971520);   // fp16 packed x
    uint16_t* wqkv = (uint16_t*)(ws + 29360128);   // fp16 packed wq|wk|wv
    uint16_t* woh  = (uint16_t*)(ws + 41943040);   // fp16 packed wo

    dim3 blk(256);
    repack_x16   <<<dim3(128, 16), blk, 0, stream>>>(x, xh);
    repack_w96_16<<<dim3(128, 64), blk, 0, stream>>>(wq, wk, wv, wqkv);
    gemm_qkv9    <<<dim3(512), dim3(512), 0, stream>>>(xh, wqkv, xq16, xk16, xv16);
    conv_kv      <<<dim3(64, 8), blk, 0, stream>>>(xk16, xv16, kvg);
    attn_mfma    <<<dim3(4352), dim3(512), 0, stream>>>(xq16, kvg, aoh, wo, woh);
    gemm_out8    <<<dim3(256), dim3(512), 0, stream>>>(aoh, woh, out);
}

// Round 16
// 347.003 us; speedup vs baseline: 1.1129x; 1.0108x over previous
//
#include <hip/hip_runtime.h>
#include <hip/hip_bf16.h>

typedef _Float16 f16_t;
typedef unsigned int uint;
typedef __attribute__((ext_vector_type(8))) _Float16 f16x8;
typedef __attribute__((ext_vector_type(4))) _Float16 f16x4;
typedef __attribute__((ext_vector_type(4))) float f32x4;
typedef __attribute__((ext_vector_type(16))) float f32x16;

#define ROPE_C (13.287712379549449f / 64.0f)   // log2(10000)/64; invf(j)=exp2(-j*ROPE_C)

// ---------------- repack fp32 [R][4096] -> packed fp16 [R/128][128 kb][128 r][32 c] ----------------
__global__ __launch_bounds__(256) void repack_x16(const float* __restrict__ src,
                                                  uint16_t* __restrict__ dh)
{
    const int p  = blockIdx.y;
    const int kb = blockIdx.x;
    const int tid = threadIdx.x;
    const int rr = tid >> 3;
    const int k4 = tid & 7;
    const int slot = k4 >> 1;
    const int so   = (k4 & 1) * 4;
    uint16_t* bh = dh + ((size_t)p * 128 + kb) * 4096;
    #pragma unroll
    for (int it = 0; it < 4; ++it) {
        const int r = it * 32 + rr;
        const float4 v = *reinterpret_cast<const float4*>(
            &src[((size_t)p * 128 + r) * 4096 + kb * 32 + k4 * 4]);
        float f[4] = {v.x, v.y, v.z, v.w};
        f16x4 h;
        #pragma unroll
        for (int e = 0; e < 4; ++e) h[e] = (f16_t)f[e];
        const int pos = r * 32 + ((slot ^ ((r >> 1) & 3)) << 3) + so;
        *reinterpret_cast<f16x4*>(&bh[pos]) = h;
    }
}

// combined wq|wk|wv -> 96-row-panel packed fp16: [64 pan][128 kb][96 r][32 c]
__global__ __launch_bounds__(256) void repack_w96_16(const float* __restrict__ wq,
                                                     const float* __restrict__ wk,
                                                     const float* __restrict__ wv,
                                                     uint16_t* __restrict__ dst)
{
    const int kb  = blockIdx.x;
    const int pan = blockIdx.y;
    const int tid = threadIdx.x;
    const int k4 = tid & 7;
    const int slot = k4 >> 1;
    const int so   = (k4 & 1) * 4;
    uint16_t* bh = dst + ((size_t)pan * 128 + kb) * 3072;
    #pragma unroll
    for (int it = 0; it < 3; ++it) {
        const int r = it * 32 + (tid >> 3);
        const int n = pan * 96 + r;
        const float* srow = (n < 4096) ? (wq + (size_t)n * 4096)
                          : (n < 5120) ? (wk + (size_t)(n - 4096) * 4096)
                                       : (wv + (size_t)(n - 5120) * 4096);
        const float4 v = *reinterpret_cast<const float4*>(srow + kb * 32 + k4 * 4);
        float f[4] = {v.x, v.y, v.z, v.w};
        f16x4 h;
        #pragma unroll
        for (int e = 0; e < 4; ++e) h[e] = (f16_t)f[e];
        const int pos = r * 32 + ((slot ^ ((r >> 1) & 3)) << 3) + so;
        *reinterpret_cast<f16x4*>(&bh[pos]) = h;
    }
}

// 128-row-panel fp16 repack (wo)
__global__ __launch_bounds__(256) void repack_h16(const float* __restrict__ src,
                                                  uint16_t* __restrict__ dh)
{
    const int p  = blockIdx.y;
    const int kb = blockIdx.x;
    const int tid = threadIdx.x;
    const int rr = tid >> 3;
    const int k4 = tid & 7;
    const int slot = k4 >> 1;
    const int so   = (k4 & 1) * 4;
    uint16_t* bh = dh + ((size_t)p * 128 + kb) * 4096;
    #pragma unroll
    for (int it = 0; it < 4; ++it) {
        const int r = it * 32 + rr;
        const float4 v = *reinterpret_cast<const float4*>(
            &src[((size_t)p * 128 + r) * 4096 + kb * 32 + k4 * 4]);
        float f[4] = {v.x, v.y, v.z, v.w};
        f16x4 h;
        #pragma unroll
        for (int e = 0; e < 4; ++e) h[e] = (f16_t)f[e];
        const int pos = r * 32 + ((slot ^ ((r >> 1) & 3)) << 3) + so;
        *reinterpret_cast<f16x4*>(&bh[pos]) = h;
    }
}

// ---------------- QKV GEMM: 128x192, fp16, BK=64, 2-buf, grid 512; 2-D XCD partition ----------------
__global__ __launch_bounds__(512) void gemm_qkv9(const uint16_t* __restrict__ xh,
                                                 const uint16_t* __restrict__ wqkv,
                                                 uint16_t* __restrict__ xq16,
                                                 uint16_t* __restrict__ xk16,
                                                 uint16_t* __restrict__ xv16)
{
    __shared__ char lds[2][40960];

    const int bid = blockIdx.x;
    const int xcd = bid & 7;
    const int i_  = bid >> 3;
    const int by = (xcd & 1) * 8 + (i_ & 7);
    const int bx = (xcd >> 1) * 8 + (i_ >> 3);
    const int tid = threadIdx.x;
    const int w = tid >> 6, lane = tid & 63;
    const int wm = w >> 2, wn = w & 3;
    const int fr = lane & 15, s4 = lane >> 4;

    const uint16_t* sp[5];
    int dof[5];
    int stridec[5];
    #pragma unroll
    for (int i = 0; i < 5; ++i) {
        const int c = w + 8 * i;
        if (c < 16) {
            const int kk = c >> 3, inner = c & 7;
            sp[i] = xh + (size_t)by * 524288 + kk * 4096 + inner * 512 + lane * 8;
            dof[i] = c * 1024;
            stridec[i] = 8192;
        } else {
            const int cb = c - 16;
            const int pan = cb / 12, rem = cb % 12;
            const int kk = rem / 6, inner = rem % 6;
            sp[i] = wqkv + (size_t)(bx * 2 + pan) * 393216 + kk * 3072 + inner * 512 + lane * 8;
            dof[i] = 16384 + cb * 1024;
            stridec[i] = 6144;
        }
    }

    f32x4 acc[4][3] = {};

    #pragma unroll
    for (int i = 0; i < 5; ++i)
        __builtin_amdgcn_global_load_lds(
            (const __attribute__((address_space(1))) void*)(sp[i]),
            (__attribute__((address_space(3))) void*)(&lds[0][0] + dof[i]), 16, 0, 0);
    asm volatile("s_waitcnt vmcnt(0)" ::: "memory");
    __builtin_amdgcn_s_barrier();
    __builtin_amdgcn_sched_barrier(0);

    for (int t = 0; t < 64; ++t) {
        const char* b = &lds[t & 1][0];
        if (t + 1 < 64) {
            char* nb = &lds[(t + 1) & 1][0];
            #pragma unroll
            for (int i = 0; i < 5; ++i)
                __builtin_amdgcn_global_load_lds(
                    (const __attribute__((address_space(1))) void*)(sp[i] + (size_t)(t + 1) * stridec[i]),
                    (__attribute__((address_space(3))) void*)(nb + dof[i]), 16, 0, 0);
        }
        #pragma unroll
        for (int kk = 0; kk < 2; ++kk) {
            f16x8 fb[3];
            #pragma unroll
            for (int j = 0; j < 3; ++j) {
                const int cbp = wn * 48 + j * 16 + fr;
                const int pan = (cbp >= 96) ? 1 : 0;
                const int rb = cbp - pan * 96;
                fb[j] = *reinterpret_cast<const f16x8*>(
                    b + 16384 + pan * 12288 + kk * 6144 + rb * 64 + ((s4 ^ ((rb >> 1) & 3)) << 4));
            }
            #pragma unroll
            for (int ri = 0; ri < 4; ++ri) {
                const int rloc = wm * 64 + ri * 16 + fr;
                f16x8 fh = *reinterpret_cast<const f16x8*>(
                    b + kk * 8192 + rloc * 64 + ((s4 ^ ((rloc >> 1) & 3)) << 4));
                __builtin_amdgcn_s_setprio(1);
                #pragma unroll
                for (int j = 0; j < 3; ++j)
                    acc[ri][j] = __builtin_amdgcn_mfma_f32_16x16x32_f16(fh, fb[j], acc[ri][j], 0, 0, 0);
                __builtin_amdgcn_s_setprio(0);
            }
        }
        asm volatile("s_waitcnt vmcnt(0)" ::: "memory");
        __builtin_amdgcn_s_barrier();
        __builtin_amdgcn_sched_barrier(0);
    }

    const int r0 = by * 128 + wm * 64 + s4 * 4;
    const int c0 = bx * 192 + wn * 48 + fr;
    #pragma unroll
    for (int ri = 0; ri < 4; ++ri)
        #pragma unroll
        for (int j = 0; j < 3; ++j) {
            const int col = c0 + j * 16;
            #pragma unroll
            for (int rr = 0; rr < 4; ++rr) {
                const int row = r0 + ri * 16 + rr;
                const f16_t v = (f16_t)acc[ri][j][rr];
                uint16_t bits;
                __builtin_memcpy(&bits, &v, 2);
                if (col < 4096)      xq16[(size_t)row * 4096 + col] = bits;
                else if (col < 5120) xk16[(size_t)row * 1024 + (col - 4096)] = bits;
                else                 xv16[(size_t)row * 1024 + (col - 5120)] = bits;
            }
        }
}

// ---------------- Output GEMM: 256x128, fp16, BK=64, 2-buf, grid 256; 2-D XCD partition ----------------
__global__ __launch_bounds__(512) void gemm_out8(const uint16_t* __restrict__ aoh,
                                                 const uint16_t* __restrict__ woh,
                                                 float* __restrict__ out)
{
    __shared__ char lds[2][49152];

    const int bid = blockIdx.x;
    const int xcd = bid & 7;
    const int i_  = bid >> 3;
    const int by = (xcd & 1) * 4 + (i_ & 3);
    const int bx = (xcd >> 1) * 8 + (i_ >> 2);
    const int tid = threadIdx.x;
    const int w = tid >> 6, lane = tid & 63;
    const int wm = w >> 2, wn = w & 3;
    const int fr = lane & 15, s4 = lane >> 4;

    const uint16_t* sp[6];
    int dof[6];
    #pragma unroll
    for (int i = 0; i < 6; ++i) {
        const int c = w + 8 * i;
        if (c < 32) {
            const int pan = c >> 4, sub = c & 15;
            sp[i] = aoh + (size_t)(2 * by + pan) * 524288 + sub * 512 + lane * 8;
            dof[i] = c * 1024;
        } else {
            sp[i] = woh + (size_t)bx * 524288 + (c - 32) * 512 + lane * 8;
            dof[i] = 32768 + (c - 32) * 1024;
        }
    }

    f32x4 acc[8][2] = {};

    #pragma unroll
    for (int i = 0; i < 6; ++i)
        __builtin_amdgcn_global_load_lds(
            (const __attribute__((address_space(1))) void*)(sp[i]),
            (__attribute__((address_space(3))) void*)(&lds[0][0] + dof[i]), 16, 0, 0);
    asm volatile("s_waitcnt vmcnt(0)" ::: "memory");
    __builtin_amdgcn_s_barrier();
    __builtin_amdgcn_sched_barrier(0);

    for (int t = 0; t < 64; ++t) {
        const char* b = &lds[t & 1][0];
        if (t + 1 < 64) {
            char* nb = &lds[(t + 1) & 1][0];
            #pragma unroll
            for (int i = 0; i < 6; ++i)
                __builtin_amdgcn_global_load_lds(
                    (const __attribute__((address_space(1))) void*)(sp[i] + (size_t)(t + 1) * 8192),
                    (__attribute__((address_space(3))) void*)(nb + dof[i]), 16, 0, 0);
        }
        #pragma unroll
        for (int kk = 0; kk < 2; ++kk) {
            f16x8 fb[2];
            #pragma unroll
            for (int j = 0; j < 2; ++j) {
                const int cbp = wn * 32 + j * 16 + fr;
                fb[j] = *reinterpret_cast<const f16x8*>(
                    b + 32768 + kk * 8192 + cbp * 64 + ((s4 ^ ((cbp >> 1) & 3)) << 4));
            }
            #pragma unroll
            for (int p = 0; p < 4; ++p) {
                f16x8 fh[2];
                #pragma unroll
                for (int f = 0; f < 2; ++f) {
                    const int rloc = p * 32 + f * 16 + fr;
                    fh[f] = *reinterpret_cast<const f16x8*>(
                        b + wm * 16384 + kk * 8192 + rloc * 64 + ((s4 ^ ((rloc >> 1) & 3)) << 4));
                }
                __builtin_amdgcn_s_setprio(1);
                #pragma unroll
                for (int f = 0; f < 2; ++f)
                    #pragma unroll
                    for (int j = 0; j < 2; ++j)
                        acc[p * 2 + f][j] = __builtin_amdgcn_mfma_f32_16x16x32_f16(fh[f], fb[j], acc[p * 2 + f][j], 0, 0, 0);
                __builtin_amdgcn_s_setprio(0);
            }
        }
        asm volatile("s_waitcnt vmcnt(0)" ::: "memory");
        __builtin_amdgcn_s_barrier();
        __builtin_amdgcn_sched_barrier(0);
    }

    const int r0 = by * 256 + wm * 128 + s4 * 4;
    const int c0 = bx * 128 + wn * 32 + fr;
    #pragma unroll
    for (int ri = 0; ri < 8; ++ri)
        #pragma unroll
        for (int j = 0; j < 2; ++j)
            #pragma unroll
            for (int rr = 0; rr < 4; ++rr)
                out[(size_t)(r0 + ri * 16 + rr) * 4096 + c0 + j * 16] = acc[ri][j][rr];
}

// ---------------- conv_kv: fp16 K/V in; rope on K; fp16 swizzled tiles out ----------------
// Tile = 8192 uint16 (16 KB): K [32 kv][128 d] at 0, Vt [128 d][32 kv] at 4096.
// V slot swizzle: slot ^= (d>>1)&3  (balanced across bank quads for PV reads).
__global__ __launch_bounds__(256) void conv_kv(const uint16_t* __restrict__ xk16,
                                               const uint16_t* __restrict__ xv16,
                                               uint16_t* __restrict__ kvg)
{
    __shared__ float V[32][129];
    const int t = blockIdx.x;
    const int h = blockIdx.y;
    const int tid = threadIdx.x;
    uint16_t* tile = kvg + ((size_t)(h * 64 + t)) * 8192;

    #pragma unroll
    for (int i = 0; i < 4; ++i) {
        const int v = i * 256 + tid;
        const int row = v >> 5, c4 = (v & 31) * 4;
        f16x4 hv = *reinterpret_cast<const f16x4*>(&xv16[(size_t)(t * 32 + row) * 1024 + h * 128 + c4]);
        #pragma unroll
        for (int e = 0; e < 4; ++e) V[row][c4 + e] = (float)hv[e];
    }

    {
        const int r = tid >> 3;
        const int d0 = (tid & 7) * 16;
        const int pos_ = t * 32 + r;
        float f[16];
        const uint16_t* kr = &xk16[(size_t)pos_ * 1024 + h * 128 + d0];
        f16x8 k0 = *reinterpret_cast<const f16x8*>(kr);
        f16x8 k1 = *reinterpret_cast<const f16x8*>(kr + 8);
        #pragma unroll
        for (int e = 0; e < 8; ++e) { f[e] = (float)k0[e]; f[8 + e] = (float)k1[e]; }
        #pragma unroll
        for (int i = 0; i < 8; ++i) {
            const int j = (d0 >> 1) + i;
            const float invf = exp2f(-(float)j * ROPE_C);
            const float ang = (float)pos_ * invf;
            float sn, cs;
            __sincosf(ang, &sn, &cs);
            const float x1 = f[2 * i], x2 = f[2 * i + 1];
            f[2 * i]     = x1 * cs - x2 * sn;
            f[2 * i + 1] = x1 * sn + x2 * cs;
        }
        #pragma unroll
        for (int cc = 0; cc < 2; ++cc) {
            f16x8 hv;
            #pragma unroll
            for (int e = 0; e < 8; ++e) hv[e] = (f16_t)f[cc * 8 + e];
            const int c = (d0 >> 3) + cc;
            const int pos = r * 128 + ((c ^ (r & 15)) << 3);
            *reinterpret_cast<f16x8*>(&tile[pos]) = hv;
        }
    }
    __syncthreads();
    {
        const int d = tid >> 1;
        const int k0 = (tid & 1) * 16;
        float g[16];
        #pragma unroll
        for (int j = 0; j < 16; ++j) g[j] = V[k0 + j][d];
        #pragma unroll
        for (int cc = 0; cc < 2; ++cc) {
            f16x8 hv;
            #pragma unroll
            for (int e = 0; e < 8; ++e) hv[e] = (f16_t)g[cc * 8 + e];
            const int c = (k0 >> 3) + cc;
            const int pos = 4096 + d * 32 + ((c ^ ((d >> 1) & 3)) << 3);
            *reinterpret_cast<f16x8*>(&tile[pos]) = hv;
        }
    }
}

// ---------------- MFMA flash attention (fp16; rope+scale on Q; defer-max; fp16 epilogue) ----------------
__device__ __forceinline__ uint cvtpkh(float lo, float hi) {
    uint r;
    asm("v_cvt_pkrtz_f16_f32 %0, %1, %2" : "=v"(r) : "v"(lo), "v"(hi));
    return r;
}
__device__ __forceinline__ void permswap(uint& a, uint& b) {
    asm("v_permlane32_swap_b32 %0, %1" : "+v"(a), "+v"(b));
}
__device__ __forceinline__ f16x8 pack4h(uint w0, uint w1, uint w2, uint w3) {
    union { uint u[4]; f16x8 v; } t;
    t.u[0] = w0; t.u[1] = w1; t.u[2] = w2; t.u[3] = w3;
    return t.v;
}

__global__ __launch_bounds__(512, 2) void attn_mfma(const uint16_t* __restrict__ xq16,
                                                    const uint16_t* __restrict__ kvg,
                                                    uint16_t* __restrict__ aoh)
{
    __shared__ char lds[2][16384];

    const int b = blockIdx.x;
    const int kvh = b & 7;
    const int r = b >> 3;
    const int h = kvh * 4 + (r & 3);
    const int q0 = (r >> 2) * 256;
    const int tid = threadIdx.x;
    const int w = tid >> 6;
    const int lane = tid & 63;
    const int ln31 = lane & 31;
    const int hi = lane >> 5;

    const int q = q0 + w * 32 + ln31;
    const uint16_t* qrow = xq16 + (size_t)q * 4096 + h * 128;
    f16x8 Qh[8];
    #pragma unroll
    for (int ks = 0; ks < 8; ++ks) {
        const int dbase = ks * 16 + hi * 8;
        f16x8 raw = *reinterpret_cast<const f16x8*>(qrow + dbase);
        float f[8];
        #pragma unroll
        for (int e = 0; e < 8; ++e) f[e] = (float)raw[e];
        #pragma unroll
        for (int i = 0; i < 4; ++i) {
            const int j = (dbase >> 1) + i;
            const float invf = exp2f(-(float)j * ROPE_C);
            const float ang = (float)q * invf;
            float sn, cs;
            __sincosf(ang, &sn, &cs);
            const float x1 = f[2 * i], x2 = f[2 * i + 1];
            f[2 * i]     = (x1 * cs - x2 * sn) * 0.08838834764831845f;
            f[2 * i + 1] = (x1 * sn + x2 * cs) * 0.08838834764831845f;
        }
        #pragma unroll
        for (int e = 0; e < 8; ++e) Qh[ks][e] = (f16_t)f[e];
    }

    const char* gkv = (const char*)kvg + (size_t)kvh * 64 * 16384;

    f32x16 oacc[4] = {{}, {}, {}, {}};
    float m = -3.0e38f, l = 0.f;

    {
        #pragma unroll
        for (int i = 0; i < 2; ++i) {
            const int chunk = i * 8 + w;
            __builtin_amdgcn_global_load_lds(
                (const __attribute__((address_space(1))) void*)(gkv + chunk * 1024 + lane * 16),
                (__attribute__((address_space(3))) void*)(&lds[0][chunk * 1024]),
                16, 0, 0);
        }
    }

    for (int t = 0; t < 64; ++t) {
        __syncthreads();
        if (t + 1 < 64) {
            const char* g = gkv + (size_t)(t + 1) * 16384;
            const int buf = (t + 1) & 1;
            #pragma unroll
            for (int i = 0; i < 2; ++i) {
                const int chunk = i * 8 + w;
                __builtin_amdgcn_global_load_lds(
                    (const __attribute__((address_space(1))) void*)(g + chunk * 1024 + lane * 16),
                    (__attribute__((address_space(3))) void*)(&lds[buf][chunk * 1024]),
                    16, 0, 0);
            }
        }
        const int cur = t & 1;
        const char* Kf = lds[cur];
        const char* Vf = lds[cur] + 8192;

        f32x16 s0 = {}, s1 = {};
        __builtin_amdgcn_s_setprio(1);
        #pragma unroll
        for (int ks = 0; ks < 8; ++ks) {
            const int byt = ln31 * 256 + ((ks * 32 + hi * 16) ^ ((ln31 & 15) << 4));
            f16x8 a = *reinterpret_cast<const f16x8*>(Kf + byt);
            if (ks & 1) s1 = __builtin_amdgcn_mfma_f32_32x32x16_f16(a, Qh[ks], s1, 0, 0, 0);
            else        s0 = __builtin_amdgcn_mfma_f32_32x32x16_f16(a, Qh[ks], s0, 0, 0, 0);
        }
        __builtin_amdgcn_s_setprio(0);
        f32x16 s = s0 + s1;

        float pmax = s[0];
        #pragma unroll
        for (int jj = 1; jj < 16; ++jj) pmax = fmaxf(pmax, s[jj]);
        pmax = fmaxf(pmax, __shfl_xor(pmax, 32));
        if (!__all(pmax - m <= 8.0f)) {
            const float mnew = fmaxf(m, pmax);
            const float corr = __expf(m - mnew);
            l *= corr;
            #pragma unroll
            for (int dt = 0; dt < 4; ++dt) oacc[dt] *= corr;
            m = mnew;
        }
        float psum = 0.f;
        #pragma unroll
        for (int jj = 0; jj < 16; ++jj) {
            float pv = __expf(s[jj] - m);
            s[jj] = pv;
            psum += pv;
        }
        psum += __shfl_xor(psum, 32);
        l += psum;

        #pragma unroll
        for (int ks = 0; ks < 2; ++ks) {
            const int b0 = ks * 8;
            uint wa = cvtpkh(s[b0 + 0], s[b0 + 1]);
            uint wb = cvtpkh(s[b0 + 2], s[b0 + 3]);
            uint wc = cvtpkh(s[b0 + 4], s[b0 + 5]);
            uint wd = cvtpkh(s[b0 + 6], s[b0 + 7]);
            permswap(wa, wc); permswap(wb, wd);
            f16x8 Pf = pack4h(wa, wb, wc, wd);
            __builtin_amdgcn_s_setprio(1);
            #pragma unroll
            for (int dt = 0; dt < 4; ++dt) {
                const int row = dt * 32 + ln31;
                const int byt = row * 64 + ((ks * 32 + hi * 16) ^ (((row >> 1) & 3) << 4));
                f16x8 vh = *reinterpret_cast<const f16x8*>(Vf + byt);
                oacc[dt] = __builtin_amdgcn_mfma_f32_32x32x16_f16(vh, Pf, oacc[dt], 0, 0, 0);
            }
            __builtin_amdgcn_s_setprio(0);
        }
    }

    const float invl = 1.0f / l;
    const int p   = q >> 7;
    const int rr_ = q & 127;
    const int rsw = (rr_ >> 1) & 3;
    #pragma unroll
    for (int dt = 0; dt < 4; ++dt) {
        const int kb = h * 4 + dt;
        uint16_t* bh = aoh + ((size_t)p * 128 + kb) * 4096;
        #pragma unroll
        for (int g4 = 0; g4 < 4; ++g4) {
            f16x4 hv;
            #pragma unroll
            for (int e = 0; e < 4; ++e)
                hv[e] = (f16_t)(oacc[dt][g4 * 4 + e] * invl);
            const int pos = rr_ * 32 + ((g4 ^ rsw) << 3) + 4 * hi;
            *reinterpret_cast<f16x4*>(&bh[pos]) = hv;
        }
    }
}

extern "C" void kernel_launch(void* const* d_in, const int* in_sizes, int n_in,
                              void* d_out, int out_size, void* d_ws, size_t ws_size,
                              hipStream_t stream)
{
    const float* x  = (const float*)d_in[0];
    const float* wq = (const float*)d_in[1];
    const float* wk = (const float*)d_in[2];
    const float* wv = (const float*)d_in[3];
    const float* wo = (const float*)d_in[4];
    float* out = (float*)d_out;

    float* ws = (float*)d_ws;
    uint16_t* xq16 = (uint16_t*)ws;                // fp16 Q [2048][4096]
    uint16_t* kvg  = (uint16_t*)(ws + 8388608);    // fp16 K/V tiles (8.4 MB)
    uint16_t* xk16 = (uint16_t*)(ws + 12582912);
    uint16_t* xv16 = (uint16_t*)(ws + 14680064);
    uint16_t* aoh  = (uint16_t*)(ws + 12582912);   // reuses xk slot after conv_kv
    uint16_t* xh   = (uint16_t*)(ws + 20971520);   // fp16 packed x
    uint16_t* wqkv = (uint16_t*)(ws + 29360128);   // fp16 packed wq|wk|wv
    uint16_t* woh  = (uint16_t*)(ws + 41943040);   // fp16 packed wo

    dim3 blk(256);
    repack_x16   <<<dim3(128, 16), blk, 0, stream>>>(x, xh);
    repack_w96_16<<<dim3(128, 64), blk, 0, stream>>>(wq, wk, wv, wqkv);
    gemm_qkv9    <<<dim3(512), dim3(512), 0, stream>>>(xh, wqkv, xq16, xk16, xv16);
    repack_h16   <<<dim3(128, 32), blk, 0, stream>>>(wo, woh);
    conv_kv      <<<dim3(64, 8), blk, 0, stream>>>(xk16, xv16, kvg);
    attn_mfma    <<<dim3(256), dim3(512), 0, stream>>>(xq16, kvg, aoh);
    gemm_out8    <<<dim3(256), dim3(512), 0, stream>>>(aoh, woh, out);
}